// Round 1
// baseline (14638.870 us; speedup 1.0000x reference)
//
#include <hip/hip_runtime.h>
#include <hip/hip_bf16.h>

// Problem constants (fixed by the bench: B=32, T0=50, F=171, H=1024, G=300)
#define Bn   32
#define Fdim 171
#define Hdim 1024
#define NG   4096            // 4*H gate rows
#define K1p  1280            // layer1 K = F+H = 1195, padded to 1280 (40 k-steps of 32)
#define K2c  2048            // layer2/3 K = 2H
#define KDd  1024            // decoder K = H
#define WDR  176             // decoder rows padded 171 -> 176
#define NBLK 192             // persistent grid: 3 layers x 64 unit-tiles

typedef __attribute__((ext_vector_type(8))) short bf16x8;
typedef __attribute__((ext_vector_type(4))) float f32x4;
typedef __hip_bfloat16 bf16;

// ---------------- workspace layout (bytes) ----------------
#define ALIGN256(x) ((((size_t)(x)) + 255) & ~(size_t)255)
constexpr size_t OFF_W1  = 0;
constexpr size_t OFF_W2  = ALIGN256(OFF_W1 + (size_t)NG * K1p * 2);
constexpr size_t OFF_W3  = ALIGN256(OFF_W2 + (size_t)NG * K2c * 2);
constexpr size_t OFF_WD  = ALIGN256(OFF_W3 + (size_t)NG * K2c * 2);
constexpr size_t OFF_B1  = ALIGN256(OFF_WD + (size_t)WDR * KDd * 2);
constexpr size_t OFF_B2  = ALIGN256(OFF_B1 + (size_t)NG * 4);
constexpr size_t OFF_B3  = ALIGN256(OFF_B2 + (size_t)NG * 4);
constexpr size_t OFF_BD  = ALIGN256(OFF_B3 + (size_t)NG * 4);
constexpr size_t OFF_AB1 = ALIGN256(OFF_BD + (size_t)WDR * 4);          // [2][32][K1p] bf16
constexpr size_t OFF_AB2 = ALIGN256(OFF_AB1 + (size_t)2 * Bn * K1p * 2); // [2][32][K2c] bf16
constexpr size_t OFF_AB3 = ALIGN256(OFF_AB2 + (size_t)2 * Bn * K2c * 2); // [2][32][K2c] bf16
constexpr size_t OFF_CB  = ALIGN256(OFF_AB3 + (size_t)2 * Bn * K2c * 2); // [3][32][H] f32
constexpr size_t OFF_BAR = ALIGN256(OFF_CB + (size_t)3 * Bn * Hdim * 4); // barrier counters
constexpr size_t WS_NEED = OFF_BAR + 256;

// gate-interleaved packed row: pr = u*64 + q*16 + rr  <->  orig row = q*1024 + u*16 + rr
__device__ __forceinline__ int orig_row(int pr) {
    int u = pr >> 6, q = (pr >> 4) & 3, rr = pr & 15;
    return q * Hdim + u * 16 + rr;
}

__device__ __forceinline__ float sigm(float x) { return 1.f / (1.f + __expf(-x)); }

__device__ __forceinline__ bf16x8 ld8(const bf16* p) {
    return *reinterpret_cast<const bf16x8*>(p);
}
__device__ __forceinline__ f32x4 mfma16(bf16x8 a, bf16x8 b, f32x4 c) {
    return __builtin_amdgcn_mfma_f32_16x16x32_bf16(a, b, c, 0, 0, 0);
}

// ---------------- prep kernels ----------------
__global__ void k_pack_w1(const float* Wih, const float* Whh, bf16* dst) {
    const size_t n = (size_t)NG * K1p;
    for (size_t i = (size_t)blockIdx.x * blockDim.x + threadIdx.x; i < n;
         i += (size_t)gridDim.x * blockDim.x) {
        int pr = (int)(i / K1p), k = (int)(i % K1p);
        int ro = orig_row(pr);
        float v = 0.f;
        if (k < Fdim)            v = Wih[(size_t)ro * Fdim + k];
        else if (k < Fdim + Hdim) v = Whh[(size_t)ro * Hdim + (k - Fdim)];
        dst[i] = __float2bfloat16(v);
    }
}

__global__ void k_pack_w23(const float* Wih, const float* Whh, bf16* dst) {
    const size_t n = (size_t)NG * K2c;
    for (size_t i = (size_t)blockIdx.x * blockDim.x + threadIdx.x; i < n;
         i += (size_t)gridDim.x * blockDim.x) {
        int pr = (int)(i / K2c), k = (int)(i % K2c);
        int ro = orig_row(pr);
        float v = (k < Hdim) ? Wih[(size_t)ro * Hdim + k]
                             : Whh[(size_t)ro * Hdim + (k - Hdim)];
        dst[i] = __float2bfloat16(v);
    }
}

__global__ void k_pack_wd(const float* Wd, bf16* dst) {
    const size_t n = (size_t)WDR * KDd;
    for (size_t i = (size_t)blockIdx.x * blockDim.x + threadIdx.x; i < n;
         i += (size_t)gridDim.x * blockDim.x) {
        int r = (int)(i / KDd), k = (int)(i % KDd);
        float v = (r < Fdim) ? Wd[(size_t)r * KDd + k] : 0.f;
        dst[i] = __float2bfloat16(v);
    }
}

__global__ void k_pack_bias(const float* bi1, const float* bh1,
                            const float* bi2, const float* bh2,
                            const float* bi3, const float* bh3,
                            const float* bd,
                            float* B1, float* B2, float* B3, float* BD) {
    const int n = 3 * NG + WDR;
    for (int i = blockIdx.x * blockDim.x + threadIdx.x; i < n;
         i += gridDim.x * blockDim.x) {
        if (i < NG)            { int ro = orig_row(i);        B1[i]        = bi1[ro] + bh1[ro]; }
        else if (i < 2 * NG)   { int ro = orig_row(i - NG);   B2[i - NG]   = bi2[ro] + bh2[ro]; }
        else if (i < 3 * NG)   { int ro = orig_row(i - 2*NG); B3[i - 2*NG] = bi3[ro] + bh3[ro]; }
        else { int r = i - 3 * NG; BD[r] = (r < Fdim) ? bd[r] : 0.f; }
    }
}

__global__ void k_init(const float* xseq, bf16* ab1, bf16* ab2, bf16* ab3,
                       float* cb, unsigned* bar, int T0) {
    const int n1 = 2 * Bn * K1p, n2 = 2 * Bn * K2c, n3 = 2 * Bn * K2c;
    const int nc = 3 * Bn * Hdim;
    const int tot = n1 + n2 + n3 + nc + 64;
    for (int i = blockIdx.x * blockDim.x + threadIdx.x; i < tot;
         i += gridDim.x * blockDim.x) {
        if (i < n1) {
            int buf = i / (Bn * K1p), rc = i % (Bn * K1p);
            int b = rc / K1p, c = rc % K1p;
            float v = 0.f;
            if (buf == 0 && c < Fdim) v = xseq[((size_t)b * T0 + 0) * Fdim + c];
            ab1[i] = __float2bfloat16(v);
        } else if (i < n1 + n2) {
            ab2[i - n1] = __float2bfloat16(0.f);
        } else if (i < n1 + n2 + n3) {
            ab3[i - n1 - n2] = __float2bfloat16(0.f);
        } else if (i < n1 + n2 + n3 + nc) {
            cb[i - n1 - n2 - n3] = 0.f;
        } else {
            bar[i - n1 - n2 - n3 - nc] = 0u;
        }
    }
}

__global__ void k_copy_orig(const float* xseq, float* out, int T, int T0) {
    const int n = Bn * T0 * Fdim;
    const size_t base = (size_t)Bn * T * Fdim;
    for (int i = blockIdx.x * blockDim.x + threadIdx.x; i < n;
         i += gridDim.x * blockDim.x) {
        out[base + i] = xseq[i];
    }
}

// ---------------- grid barrier (all NBLK blocks co-resident) ----------------
__device__ __forceinline__ void gbar(unsigned* cnt, unsigned* rel, unsigned target) {
    __syncthreads();
    if (threadIdx.x == 0) {
        __threadfence();  // flush this block's writes to device scope
        unsigned arrived =
            __hip_atomic_fetch_add(cnt, 1u, __ATOMIC_RELAXED, __HIP_MEMORY_SCOPE_AGENT) + 1u;
        if (arrived == (unsigned)NBLK * target) {
            __hip_atomic_store(rel, target, __ATOMIC_RELAXED, __HIP_MEMORY_SCOPE_AGENT);
        } else {
            unsigned v;
            do {
                __builtin_amdgcn_s_sleep(4);
                v = __hip_atomic_load(rel, __ATOMIC_RELAXED, __HIP_MEMORY_SCOPE_AGENT);
            } while (v < target);
        }
        __threadfence();  // acquire: invalidate stale caches before reading others' data
    }
    __syncthreads();
}

// ---------------- persistent LSTM kernel ----------------
// grid = NBLK blocks x 256 threads. block -> (layer = bid/64, unit-tile ut = bid%64).
// Each block computes gates[32 x 64] (i,f,g,o interleaved for 16 hidden units),
// K split 4-ways across the block's waves, LDS reduce, elementwise c/h update.
// Phase B: blocks 0..10 decoder ([32x16] tiles over Wd), block 11 stages next cond input.
__global__ __launch_bounds__(256, 1) void k_lstm(
    const float* __restrict__ xseq, float* __restrict__ out,
    const bf16* __restrict__ W1, const bf16* __restrict__ W2,
    const bf16* __restrict__ W3, const bf16* __restrict__ WD,
    const float* __restrict__ b1, const float* __restrict__ b2,
    const float* __restrict__ b3, const float* __restrict__ bdp,
    bf16* ab1, bf16* ab2, bf16* ab3, float* cb,
    unsigned* bar, int T0, int T) {
    __shared__ float red[4][32][64];

    const int tid = threadIdx.x;
    const int w = tid >> 6;
    const int lane = tid & 63;
    const int col = lane & 15;          // n-col within 16 / A-row within 16
    const int kb8 = (lane >> 4) << 3;   // k sub-block offset (0,8,16,24)
    const int bid = blockIdx.x;
    const int layer = bid >> 6;         // 0,1,2
    const int ut = bid & 63;            // hidden-unit tile (16 units)

    unsigned* cnt = bar;
    unsigned* rel = bar + 16;           // separate cacheline

    const bf16* Wl = (layer == 0) ? W1 : (layer == 1) ? W2 : W3;
    const float* bl = (layer == 0) ? b1 : (layer == 1) ? b2 : b3;
    const int K = (layer == 0) ? K1p : K2c;
    const int KQ = K >> 2;              // per-wave K chunk
    bf16* abIn = (layer == 0) ? ab1 : (layer == 1) ? ab2 : ab3;

    unsigned bcount = 0;

    for (int t = 0; t < T; ++t) {
        const int p = t & 1;

        // ---------- phase A: gate GEMM + state update ----------
        {
            const bf16* Ar = abIn + (size_t)p * Bn * K;
            const bf16* Wrow = Wl + (size_t)(ut * 64) * K;
            f32x4 acc[2][4] = {};
            const int k0 = w * KQ, k1e = k0 + KQ;
#pragma unroll 2
            for (int k = k0; k < k1e; k += 32) {
                bf16x8 a0 = ld8(Ar + (size_t)col * K + k + kb8);
                bf16x8 a1 = ld8(Ar + (size_t)(col + 16) * K + k + kb8);
                const bf16* wp = Wrow + (size_t)col * K + k + kb8;
#pragma unroll
                for (int q = 0; q < 4; ++q) {
                    bf16x8 bq = ld8(wp + (size_t)q * 16 * K);
                    acc[0][q] = mfma16(a0, bq, acc[0][q]);
                    acc[1][q] = mfma16(a1, bq, acc[1][q]);
                }
            }
            // dump partials to LDS: C/D layout row=(lane>>4)*4+r, col=lane&15
#pragma unroll
            for (int mt = 0; mt < 2; ++mt)
#pragma unroll
                for (int q = 0; q < 4; ++q)
#pragma unroll
                    for (int r = 0; r < 4; ++r)
                        red[w][mt * 16 + (lane >> 4) * 4 + r][q * 16 + col] = acc[mt][q][r];
            __syncthreads();

            // elementwise: 512 (b, jj) pairs over 256 threads
            bf16* ab1w = ab1 + (size_t)(p ^ 1) * Bn * K1p;
            bf16* ab2w = ab2 + (size_t)(p ^ 1) * Bn * K2c;
            bf16* ab3w = ab3 + (size_t)(p ^ 1) * Bn * K2c;
#pragma unroll
            for (int pi = 0; pi < 2; ++pi) {
                int pair = tid * 2 + pi;
                int b = pair >> 4, jj = pair & 15;
                float s[4];
#pragma unroll
                for (int q = 0; q < 4; ++q)
                    s[q] = red[0][b][q * 16 + jj] + red[1][b][q * 16 + jj] +
                           red[2][b][q * 16 + jj] + red[3][b][q * 16 + jj] +
                           bl[ut * 64 + q * 16 + jj];
                int j = ut * 16 + jj;
                size_t cidx = ((size_t)layer * Bn + b) * Hdim + j;
                float cold = cb[cidx];
                float cn = sigm(s[1]) * cold + sigm(s[0]) * tanhf(s[2]);
                float hn = sigm(s[3]) * tanhf(cn);
                cb[cidx] = cn;
                bf16 hb = __float2bfloat16(hn);
                if (layer == 0) {
                    ab1w[(size_t)b * K1p + Fdim + j] = hb;
                    ab2w[(size_t)b * K2c + j] = hb;
                } else if (layer == 1) {
                    ab2w[(size_t)b * K2c + Hdim + j] = hb;
                    ab3w[(size_t)b * K2c + j] = hb;
                } else {
                    ab3w[(size_t)b * K2c + Hdim + j] = hb;
                }
            }
        }
        gbar(cnt, rel, ++bcount);

        // ---------- phase B: decoder + next-input staging ----------
        if (bid < 11) {
            // out(t)[32 x 16] tile: cols bid*16.., K=1024 over nh2 (ab3[p^1] cols 1024..)
            const bf16* Ad = ab3 + (size_t)(p ^ 1) * Bn * K2c + Hdim;
            const bf16* Wrowd = WD + (size_t)(bid * 16) * KDd;
            f32x4 dacc[2] = {};
            const int dk0 = w * (KDd / 4), dk1 = dk0 + (KDd / 4);
#pragma unroll 2
            for (int k = dk0; k < dk1; k += 32) {
                bf16x8 a0 = ld8(Ad + (size_t)col * K2c + k + kb8);
                bf16x8 a1 = ld8(Ad + (size_t)(col + 16) * K2c + k + kb8);
                bf16x8 bq = ld8(Wrowd + (size_t)col * KDd + k + kb8);
                dacc[0] = mfma16(a0, bq, dacc[0]);
                dacc[1] = mfma16(a1, bq, dacc[1]);
            }
            __syncthreads();
#pragma unroll
            for (int mt = 0; mt < 2; ++mt)
#pragma unroll
                for (int r = 0; r < 4; ++r)
                    red[w][mt * 16 + (lane >> 4) * 4 + r][col] = dacc[mt][r];
            __syncthreads();
#pragma unroll
            for (int pi = 0; pi < 2; ++pi) {
                int pair = tid * 2 + pi;
                int b = pair >> 4, jj = pair & 15;
                int f = bid * 16 + jj;
                if (f < Fdim) {
                    float v = red[0][b][jj] + red[1][b][jj] + red[2][b][jj] +
                              red[3][b][jj] + bdp[f];
                    out[(size_t)b * ((size_t)T * Fdim) + (size_t)t * Fdim + f] = v;
                    if (t >= T0 - 1)  // out(t) is the input x(t+1) in the generative phase
                        ab1[(size_t)(p ^ 1) * Bn * K1p + (size_t)b * K1p + f] =
                            __float2bfloat16(v);
                }
            }
        } else if (bid == 11) {
            if (t + 1 < T0) {  // stage conditioned input x(t+1)
                for (int i = tid; i < Bn * Fdim; i += 256) {
                    int b = i / Fdim, f = i % Fdim;
                    ab1[(size_t)(p ^ 1) * Bn * K1p + (size_t)b * K1p + f] =
                        __float2bfloat16(xseq[((size_t)b * T0 + (t + 1)) * Fdim + f]);
                }
            }
        }
        gbar(cnt, rel, ++bcount);
    }
}

// ---------------- host launch ----------------
extern "C" void kernel_launch(void* const* d_in, const int* in_sizes, int n_in,
                              void* d_out, int out_size, void* d_ws, size_t ws_size,
                              hipStream_t stream) {
    const float* xseq = (const float*)d_in[0];
    const float* Wih1 = (const float*)d_in[2];
    const float* Whh1 = (const float*)d_in[3];
    const float* bih1 = (const float*)d_in[4];
    const float* bhh1 = (const float*)d_in[5];
    const float* Wih2 = (const float*)d_in[6];
    const float* Whh2 = (const float*)d_in[7];
    const float* bih2 = (const float*)d_in[8];
    const float* bhh2 = (const float*)d_in[9];
    const float* Wih3 = (const float*)d_in[10];
    const float* Whh3 = (const float*)d_in[11];
    const float* bih3 = (const float*)d_in[12];
    const float* bhh3 = (const float*)d_in[13];
    const float* Wd   = (const float*)d_in[14];
    const float* bd   = (const float*)d_in[15];

    const int T0 = in_sizes[0] / (Bn * Fdim);                 // 50
    const int T  = out_size / (Bn * Fdim) - T0;               // 350

    char* ws = (char*)d_ws;
    bf16*  pW1 = (bf16*)(ws + OFF_W1);
    bf16*  pW2 = (bf16*)(ws + OFF_W2);
    bf16*  pW3 = (bf16*)(ws + OFF_W3);
    bf16*  pWD = (bf16*)(ws + OFF_WD);
    float* pB1 = (float*)(ws + OFF_B1);
    float* pB2 = (float*)(ws + OFF_B2);
    float* pB3 = (float*)(ws + OFF_B3);
    float* pBD = (float*)(ws + OFF_BD);
    bf16*  ab1 = (bf16*)(ws + OFF_AB1);
    bf16*  ab2 = (bf16*)(ws + OFF_AB2);
    bf16*  ab3 = (bf16*)(ws + OFF_AB3);
    float* cbp = (float*)(ws + OFF_CB);
    unsigned* bar = (unsigned*)(ws + OFF_BAR);
    float* out = (float*)d_out;

    (void)ws_size; (void)n_in;  // WS_NEED ~= 45.6 MB

    hipLaunchKernelGGL(k_pack_w1, dim3(1024), dim3(256), 0, stream, Wih1, Whh1, pW1);
    hipLaunchKernelGGL(k_pack_w23, dim3(1024), dim3(256), 0, stream, Wih2, Whh2, pW2);
    hipLaunchKernelGGL(k_pack_w23, dim3(1024), dim3(256), 0, stream, Wih3, Whh3, pW3);
    hipLaunchKernelGGL(k_pack_wd, dim3(704), dim3(256), 0, stream, Wd, pWD);
    hipLaunchKernelGGL(k_pack_bias, dim3(49), dim3(256), 0, stream,
                       bih1, bhh1, bih2, bhh2, bih3, bhh3, bd, pB1, pB2, pB3, pBD);
    hipLaunchKernelGGL(k_init, dim3(1024), dim3(256), 0, stream,
                       xseq, ab1, ab2, ab3, cbp, bar, T0);
    hipLaunchKernelGGL(k_lstm, dim3(NBLK), dim3(256), 0, stream,
                       xseq, out, pW1, pW2, pW3, pWD, pB1, pB2, pB3, pBD,
                       ab1, ab2, ab3, cbp, bar, T0, T);
    hipLaunchKernelGGL(k_copy_orig, dim3(1069), dim3(256), 0, stream, xseq, out, T, T0);
}

// Round 2
// 11865.251 us; speedup vs baseline: 1.2338x; 1.2338x over previous
//
#include <hip/hip_runtime.h>
#include <hip/hip_bf16.h>

// Problem constants (fixed by the bench: B=32, T0=50, F=171, H=1024, G=300)
#define Bn   32
#define Fdim 171
#define Hdim 1024
#define NG   4096            // 4*H gate rows
#define K1p  1280            // layer1 K = F+H = 1195, padded to 1280 (40 k-steps of 32)
#define K2c  2048            // layer2/3 K = 2H
#define KDd  1024            // decoder K = H
#define WDR  176             // decoder rows padded 171 -> 176
#define NBLK 192             // persistent grid: 3 layers x 64 unit-tiles

typedef __attribute__((ext_vector_type(8))) short bf16x8;
typedef __attribute__((ext_vector_type(4))) float f32x4;
typedef __hip_bfloat16 bf16;

// ---------------- workspace layout (bytes) ----------------
#define ALIGN256(x) ((((size_t)(x)) + 255) & ~(size_t)255)
constexpr size_t OFF_W1  = 0;
constexpr size_t OFF_W2  = ALIGN256(OFF_W1 + (size_t)NG * K1p * 2);
constexpr size_t OFF_W3  = ALIGN256(OFF_W2 + (size_t)NG * K2c * 2);
constexpr size_t OFF_WD  = ALIGN256(OFF_W3 + (size_t)NG * K2c * 2);
constexpr size_t OFF_B1  = ALIGN256(OFF_WD + (size_t)WDR * KDd * 2);
constexpr size_t OFF_B2  = ALIGN256(OFF_B1 + (size_t)NG * 4);
constexpr size_t OFF_B3  = ALIGN256(OFF_B2 + (size_t)NG * 4);
constexpr size_t OFF_BD  = ALIGN256(OFF_B3 + (size_t)NG * 4);
constexpr size_t OFF_AB1 = ALIGN256(OFF_BD + (size_t)WDR * 4);          // [2][32][K1p] bf16
constexpr size_t OFF_AB2 = ALIGN256(OFF_AB1 + (size_t)2 * Bn * K1p * 2); // [2][32][K2c] bf16
constexpr size_t OFF_AB3 = ALIGN256(OFF_AB2 + (size_t)2 * Bn * K2c * 2); // [2][32][K2c] bf16
constexpr size_t OFF_CB  = ALIGN256(OFF_AB3 + (size_t)2 * Bn * K2c * 2); // [3][32][H] f32
constexpr size_t OFF_BAR = ALIGN256(OFF_CB + (size_t)3 * Bn * Hdim * 4); // barrier flags
constexpr size_t WS_NEED = OFF_BAR + 2048;

// gate-interleaved packed row: pr = u*64 + q*16 + rr  <->  orig row = q*1024 + u*16 + rr
__device__ __forceinline__ int orig_row(int pr) {
    int u = pr >> 6, q = (pr >> 4) & 3, rr = pr & 15;
    return q * Hdim + u * 16 + rr;
}

__device__ __forceinline__ float sigm(float x) { return 1.f / (1.f + __expf(-x)); }

__device__ __forceinline__ bf16x8 ld8(const bf16* p) {
    return *reinterpret_cast<const bf16x8*>(p);
}
__device__ __forceinline__ f32x4 mfma16(bf16x8 a, bf16x8 b, f32x4 c) {
    return __builtin_amdgcn_mfma_f32_16x16x32_bf16(a, b, c, 0, 0, 0);
}

// ---------------- prep kernels ----------------
__global__ void k_pack_w1(const float* Wih, const float* Whh, bf16* dst) {
    const size_t n = (size_t)NG * K1p;
    for (size_t i = (size_t)blockIdx.x * blockDim.x + threadIdx.x; i < n;
         i += (size_t)gridDim.x * blockDim.x) {
        int pr = (int)(i / K1p), k = (int)(i % K1p);
        int ro = orig_row(pr);
        float v = 0.f;
        if (k < Fdim)            v = Wih[(size_t)ro * Fdim + k];
        else if (k < Fdim + Hdim) v = Whh[(size_t)ro * Hdim + (k - Fdim)];
        dst[i] = __float2bfloat16(v);
    }
}

__global__ void k_pack_w23(const float* Wih, const float* Whh, bf16* dst) {
    const size_t n = (size_t)NG * K2c;
    for (size_t i = (size_t)blockIdx.x * blockDim.x + threadIdx.x; i < n;
         i += (size_t)gridDim.x * blockDim.x) {
        int pr = (int)(i / K2c), k = (int)(i % K2c);
        int ro = orig_row(pr);
        float v = (k < Hdim) ? Wih[(size_t)ro * Hdim + k]
                             : Whh[(size_t)ro * Hdim + (k - Hdim)];
        dst[i] = __float2bfloat16(v);
    }
}

__global__ void k_pack_wd(const float* Wd, bf16* dst) {
    const size_t n = (size_t)WDR * KDd;
    for (size_t i = (size_t)blockIdx.x * blockDim.x + threadIdx.x; i < n;
         i += (size_t)gridDim.x * blockDim.x) {
        int r = (int)(i / KDd), k = (int)(i % KDd);
        float v = (r < Fdim) ? Wd[(size_t)r * KDd + k] : 0.f;
        dst[i] = __float2bfloat16(v);
    }
}

__global__ void k_pack_bias(const float* bi1, const float* bh1,
                            const float* bi2, const float* bh2,
                            const float* bi3, const float* bh3,
                            const float* bd,
                            float* B1, float* B2, float* B3, float* BD) {
    const int n = 3 * NG + WDR;
    for (int i = blockIdx.x * blockDim.x + threadIdx.x; i < n;
         i += gridDim.x * blockDim.x) {
        if (i < NG)            { int ro = orig_row(i);        B1[i]        = bi1[ro] + bh1[ro]; }
        else if (i < 2 * NG)   { int ro = orig_row(i - NG);   B2[i - NG]   = bi2[ro] + bh2[ro]; }
        else if (i < 3 * NG)   { int ro = orig_row(i - 2*NG); B3[i - 2*NG] = bi3[ro] + bh3[ro]; }
        else { int r = i - 3 * NG; BD[r] = (r < Fdim) ? bd[r] : 0.f; }
    }
}

__global__ void k_init(const float* xseq, bf16* ab1, bf16* ab2, bf16* ab3,
                       float* cb, unsigned* bar, int T0) {
    const int n1 = 2 * Bn * K1p, n2 = 2 * Bn * K2c, n3 = 2 * Bn * K2c;
    const int nc = 3 * Bn * Hdim;
    const int tot = n1 + n2 + n3 + nc + 512;
    for (int i = blockIdx.x * blockDim.x + threadIdx.x; i < tot;
         i += gridDim.x * blockDim.x) {
        if (i < n1) {
            int buf = i / (Bn * K1p), rc = i % (Bn * K1p);
            int b = rc / K1p, c = rc % K1p;
            float v = 0.f;
            if (buf == 0 && c < Fdim) v = xseq[((size_t)b * T0 + 0) * Fdim + c];
            ab1[i] = __float2bfloat16(v);
        } else if (i < n1 + n2) {
            ab2[i - n1] = __float2bfloat16(0.f);
        } else if (i < n1 + n2 + n3) {
            ab3[i - n1 - n2] = __float2bfloat16(0.f);
        } else if (i < n1 + n2 + n3 + nc) {
            cb[i - n1 - n2 - n3] = 0.f;
        } else {
            bar[i - n1 - n2 - n3 - nc] = 0u;
        }
    }
}

__global__ void k_copy_orig(const float* xseq, float* out, int T, int T0) {
    const int n = Bn * T0 * Fdim;
    const size_t base = (size_t)Bn * T * Fdim;
    for (int i = blockIdx.x * blockDim.x + threadIdx.x; i < n;
         i += gridDim.x * blockDim.x) {
        out[base + i] = xseq[i];
    }
}

// ---------------- grid barrier v2: flag array + central poller ----------------
// Arrival: each block stores its step count to its OWN flag slot (parallel, no RMW).
// Wave 0 of block 0 polls all 192 flags with 3 vector loads + __all ballot, then
// stores a release word that the other 191 blocks poll read-only (no serialization).
__device__ __forceinline__ void gbar(unsigned* bar, unsigned target) {
    const int tid = threadIdx.x;
    const int bid = blockIdx.x;
    unsigned* flags = bar;          // [0..191]
    unsigned* rel = bar + 448;      // separate cacheline (byte 1792)
    __syncthreads();
    if (tid < 64) {
        if (tid == 0) {
            __threadfence();  // release: make this block's writes visible first
            __hip_atomic_store(&flags[bid], target, __ATOMIC_RELAXED,
                               __HIP_MEMORY_SCOPE_AGENT);
        }
        if (bid == 0) {
            for (;;) {
                unsigned v0 = __hip_atomic_load(&flags[tid], __ATOMIC_RELAXED,
                                                __HIP_MEMORY_SCOPE_AGENT);
                unsigned v1 = __hip_atomic_load(&flags[tid + 64], __ATOMIC_RELAXED,
                                                __HIP_MEMORY_SCOPE_AGENT);
                unsigned v2 = __hip_atomic_load(&flags[tid + 128], __ATOMIC_RELAXED,
                                                __HIP_MEMORY_SCOPE_AGENT);
                if (__all(v0 >= target && v1 >= target && v2 >= target)) break;
                __builtin_amdgcn_s_sleep(1);
            }
            __threadfence();  // acquire for block 0's subsequent reads
            if (tid == 0)
                __hip_atomic_store(rel, target, __ATOMIC_RELAXED,
                                   __HIP_MEMORY_SCOPE_AGENT);
        } else if (tid == 0) {
            unsigned v;
            do {
                __builtin_amdgcn_s_sleep(2);
                v = __hip_atomic_load(rel, __ATOMIC_RELAXED,
                                      __HIP_MEMORY_SCOPE_AGENT);
            } while (v < target);
            __threadfence();  // acquire: invalidate stale caches before reading
        }
    }
    __syncthreads();
}

// ---------------- persistent LSTM kernel ----------------
// grid = NBLK blocks x 256 threads. block -> (layer = bid/64, unit-tile ut = bid%64).
// Each block computes gates[32 x 64] (i,f,g,o interleaved for 16 hidden units),
// K split 4-ways across the block's waves, LDS reduce, elementwise c/h update.
// Phase B: blocks 0..10 decoder ([32x16] tiles over Wd), block 11 stages next cond input.
__global__ __launch_bounds__(256, 1) void k_lstm(
    const float* __restrict__ xseq, float* __restrict__ out,
    const bf16* __restrict__ W1, const bf16* __restrict__ W2,
    const bf16* __restrict__ W3, const bf16* __restrict__ WD,
    const float* __restrict__ b1, const float* __restrict__ b2,
    const float* __restrict__ b3, const float* __restrict__ bdp,
    bf16* ab1, bf16* ab2, bf16* ab3, float* cb,
    unsigned* bar, int T0, int T) {
    __shared__ float red[4][32][64];

    const int tid = threadIdx.x;
    const int w = tid >> 6;
    const int lane = tid & 63;
    const int col = lane & 15;          // n-col within 16 / A-row within 16
    const int kb8 = (lane >> 4) << 3;   // k sub-block offset (0,8,16,24)
    const int bid = blockIdx.x;
    const int layer = bid >> 6;         // 0,1,2
    const int ut = bid & 63;            // hidden-unit tile (16 units)

    const bf16* Wl = (layer == 0) ? W1 : (layer == 1) ? W2 : W3;
    const float* bl = (layer == 0) ? b1 : (layer == 1) ? b2 : b3;
    const int K = (layer == 0) ? K1p : K2c;
    const int KQ = K >> 2;              // per-wave K chunk
    bf16* abIn = (layer == 0) ? ab1 : (layer == 1) ? ab2 : ab3;

    unsigned bcount = 0;

    for (int t = 0; t < T; ++t) {
        const int p = t & 1;

        // ---------- phase A: gate GEMM + state update ----------
        {
            const bf16* Ar = abIn + (size_t)p * Bn * K;
            const bf16* Wrow = Wl + (size_t)(ut * 64) * K;
            f32x4 acc[2][4] = {};
            const int k0 = w * KQ, k1e = k0 + KQ;
#pragma unroll 4
            for (int k = k0; k < k1e; k += 32) {
                bf16x8 a0 = ld8(Ar + (size_t)col * K + k + kb8);
                bf16x8 a1 = ld8(Ar + (size_t)(col + 16) * K + k + kb8);
                const bf16* wp = Wrow + (size_t)col * K + k + kb8;
#pragma unroll
                for (int q = 0; q < 4; ++q) {
                    bf16x8 bq = ld8(wp + (size_t)q * 16 * K);
                    acc[0][q] = mfma16(a0, bq, acc[0][q]);
                    acc[1][q] = mfma16(a1, bq, acc[1][q]);
                }
            }
            // dump partials to LDS: C/D layout row=(lane>>4)*4+r, col=lane&15
#pragma unroll
            for (int mt = 0; mt < 2; ++mt)
#pragma unroll
                for (int q = 0; q < 4; ++q)
#pragma unroll
                    for (int r = 0; r < 4; ++r)
                        red[w][mt * 16 + (lane >> 4) * 4 + r][q * 16 + col] = acc[mt][q][r];
            __syncthreads();

            // elementwise: 512 (b, jj) pairs over 256 threads
            bf16* ab1w = ab1 + (size_t)(p ^ 1) * Bn * K1p;
            bf16* ab2w = ab2 + (size_t)(p ^ 1) * Bn * K2c;
            bf16* ab3w = ab3 + (size_t)(p ^ 1) * Bn * K2c;
#pragma unroll
            for (int pi = 0; pi < 2; ++pi) {
                int pair = tid * 2 + pi;
                int b = pair >> 4, jj = pair & 15;
                float s[4];
#pragma unroll
                for (int q = 0; q < 4; ++q)
                    s[q] = red[0][b][q * 16 + jj] + red[1][b][q * 16 + jj] +
                           red[2][b][q * 16 + jj] + red[3][b][q * 16 + jj] +
                           bl[ut * 64 + q * 16 + jj];
                int j = ut * 16 + jj;
                size_t cidx = ((size_t)layer * Bn + b) * Hdim + j;
                float cold = cb[cidx];
                float cn = sigm(s[1]) * cold + sigm(s[0]) * tanhf(s[2]);
                float hn = sigm(s[3]) * tanhf(cn);
                cb[cidx] = cn;
                bf16 hb = __float2bfloat16(hn);
                if (layer == 0) {
                    ab1w[(size_t)b * K1p + Fdim + j] = hb;
                    ab2w[(size_t)b * K2c + j] = hb;
                } else if (layer == 1) {
                    ab2w[(size_t)b * K2c + Hdim + j] = hb;
                    ab3w[(size_t)b * K2c + j] = hb;
                } else {
                    ab3w[(size_t)b * K2c + Hdim + j] = hb;
                }
            }
        }
        gbar(bar, ++bcount);

        // ---------- phase B: decoder + next-input staging ----------
        if (bid < 11) {
            // out(t)[32 x 16] tile: cols bid*16.., K=1024 over nh2 (ab3[p^1] cols 1024..)
            const bf16* Ad = ab3 + (size_t)(p ^ 1) * Bn * K2c + Hdim;
            const bf16* Wrowd = WD + (size_t)(bid * 16) * KDd;
            f32x4 dacc[2] = {};
            const int dk0 = w * (KDd / 4), dk1 = dk0 + (KDd / 4);
#pragma unroll 4
            for (int k = dk0; k < dk1; k += 32) {
                bf16x8 a0 = ld8(Ad + (size_t)col * K2c + k + kb8);
                bf16x8 a1 = ld8(Ad + (size_t)(col + 16) * K2c + k + kb8);
                bf16x8 bq = ld8(Wrowd + (size_t)col * KDd + k + kb8);
                dacc[0] = mfma16(a0, bq, dacc[0]);
                dacc[1] = mfma16(a1, bq, dacc[1]);
            }
            __syncthreads();
#pragma unroll
            for (int mt = 0; mt < 2; ++mt)
#pragma unroll
                for (int r = 0; r < 4; ++r)
                    red[w][mt * 16 + (lane >> 4) * 4 + r][col] = dacc[mt][r];
            __syncthreads();
#pragma unroll
            for (int pi = 0; pi < 2; ++pi) {
                int pair = tid * 2 + pi;
                int b = pair >> 4, jj = pair & 15;
                int f = bid * 16 + jj;
                if (f < Fdim) {
                    float v = red[0][b][jj] + red[1][b][jj] + red[2][b][jj] +
                              red[3][b][jj] + bdp[f];
                    out[(size_t)b * ((size_t)T * Fdim) + (size_t)t * Fdim + f] = v;
                    if (t >= T0 - 1)  // out(t) is the input x(t+1) in the generative phase
                        ab1[(size_t)(p ^ 1) * Bn * K1p + (size_t)b * K1p + f] =
                            __float2bfloat16(v);
                }
            }
        } else if (bid == 11) {
            if (t + 1 < T0) {  // stage conditioned input x(t+1)
                for (int i = tid; i < Bn * Fdim; i += 256) {
                    int b = i / Fdim, f = i % Fdim;
                    ab1[(size_t)(p ^ 1) * Bn * K1p + (size_t)b * K1p + f] =
                        __float2bfloat16(xseq[((size_t)b * T0 + (t + 1)) * Fdim + f]);
                }
            }
        }
        gbar(bar, ++bcount);
    }
}

// ---------------- host launch ----------------
extern "C" void kernel_launch(void* const* d_in, const int* in_sizes, int n_in,
                              void* d_out, int out_size, void* d_ws, size_t ws_size,
                              hipStream_t stream) {
    const float* xseq = (const float*)d_in[0];
    const float* Wih1 = (const float*)d_in[2];
    const float* Whh1 = (const float*)d_in[3];
    const float* bih1 = (const float*)d_in[4];
    const float* bhh1 = (const float*)d_in[5];
    const float* Wih2 = (const float*)d_in[6];
    const float* Whh2 = (const float*)d_in[7];
    const float* bih2 = (const float*)d_in[8];
    const float* bhh2 = (const float*)d_in[9];
    const float* Wih3 = (const float*)d_in[10];
    const float* Whh3 = (const float*)d_in[11];
    const float* bih3 = (const float*)d_in[12];
    const float* bhh3 = (const float*)d_in[13];
    const float* Wd   = (const float*)d_in[14];
    const float* bd   = (const float*)d_in[15];

    const int T0 = in_sizes[0] / (Bn * Fdim);                 // 50
    const int T  = out_size / (Bn * Fdim) - T0;               // 350

    char* ws = (char*)d_ws;
    bf16*  pW1 = (bf16*)(ws + OFF_W1);
    bf16*  pW2 = (bf16*)(ws + OFF_W2);
    bf16*  pW3 = (bf16*)(ws + OFF_W3);
    bf16*  pWD = (bf16*)(ws + OFF_WD);
    float* pB1 = (float*)(ws + OFF_B1);
    float* pB2 = (float*)(ws + OFF_B2);
    float* pB3 = (float*)(ws + OFF_B3);
    float* pBD = (float*)(ws + OFF_BD);
    bf16*  ab1 = (bf16*)(ws + OFF_AB1);
    bf16*  ab2 = (bf16*)(ws + OFF_AB2);
    bf16*  ab3 = (bf16*)(ws + OFF_AB3);
    float* cbp = (float*)(ws + OFF_CB);
    unsigned* bar = (unsigned*)(ws + OFF_BAR);
    float* out = (float*)d_out;

    (void)ws_size; (void)n_in;  // WS_NEED ~= 45.6 MB

    hipLaunchKernelGGL(k_pack_w1, dim3(1024), dim3(256), 0, stream, Wih1, Whh1, pW1);
    hipLaunchKernelGGL(k_pack_w23, dim3(1024), dim3(256), 0, stream, Wih2, Whh2, pW2);
    hipLaunchKernelGGL(k_pack_w23, dim3(1024), dim3(256), 0, stream, Wih3, Whh3, pW3);
    hipLaunchKernelGGL(k_pack_wd, dim3(704), dim3(256), 0, stream, Wd, pWD);
    hipLaunchKernelGGL(k_pack_bias, dim3(49), dim3(256), 0, stream,
                       bih1, bhh1, bih2, bhh2, bih3, bhh3, bd, pB1, pB2, pB3, pBD);
    hipLaunchKernelGGL(k_init, dim3(1024), dim3(256), 0, stream,
                       xseq, ab1, ab2, ab3, cbp, bar, T0);
    hipLaunchKernelGGL(k_lstm, dim3(NBLK), dim3(256), 0, stream,
                       xseq, out, pW1, pW2, pW3, pWD, pB1, pB2, pB3, pBD,
                       ab1, ab2, ab3, cbp, bar, T0, T);
    hipLaunchKernelGGL(k_copy_orig, dim3(1069), dim3(256), 0, stream, xseq, out, T, T0);
}

// Round 3
// 9328.813 us; speedup vs baseline: 1.5692x; 1.2719x over previous
//
#include <hip/hip_runtime.h>
#include <hip/hip_bf16.h>

// Problem constants (fixed by the bench: B=32, T0=50, F=171, H=1024, G=300)
#define Bn   32
#define Fdim 171
#define XPAD 172             // x-region padded so h-region starts 4B-aligned
#define Hdim 1024
#define NG   4096            // 4*H gate rows
#define K1p  1280            // layer1 K = XPAD+H = 1196, padded to 1280
#define K2c  2048            // layer2/3 K = 2H
#define KDd  1024            // decoder K = H
#define WDR  176             // decoder rows padded 171 -> 176
#define NBLK 192             // persistent grid: 3 layers x 64 unit-tiles

typedef __attribute__((ext_vector_type(8))) short bf16x8;
typedef __attribute__((ext_vector_type(4))) float f32x4;
typedef __hip_bfloat16 bf16;

// ---------------- workspace layout (bytes) ----------------
#define ALIGN256(x) ((((size_t)(x)) + 255) & ~(size_t)255)
constexpr size_t OFF_W1  = 0;
constexpr size_t OFF_W2  = ALIGN256(OFF_W1 + (size_t)NG * K1p * 2);
constexpr size_t OFF_W3  = ALIGN256(OFF_W2 + (size_t)NG * K2c * 2);
constexpr size_t OFF_WD  = ALIGN256(OFF_W3 + (size_t)NG * K2c * 2);
constexpr size_t OFF_B1  = ALIGN256(OFF_WD + (size_t)WDR * KDd * 2);
constexpr size_t OFF_B2  = ALIGN256(OFF_B1 + (size_t)NG * 4);
constexpr size_t OFF_B3  = ALIGN256(OFF_B2 + (size_t)NG * 4);
constexpr size_t OFF_BD  = ALIGN256(OFF_B3 + (size_t)NG * 4);
constexpr size_t OFF_AB1 = ALIGN256(OFF_BD + (size_t)WDR * 4);          // [2][32][K1p] bf16
constexpr size_t OFF_AB2 = ALIGN256(OFF_AB1 + (size_t)2 * Bn * K1p * 2); // [2][32][K2c] bf16
constexpr size_t OFF_AB3 = ALIGN256(OFF_AB2 + (size_t)2 * Bn * K2c * 2); // [2][32][K2c] bf16
constexpr size_t OFF_CB  = ALIGN256(OFF_AB3 + (size_t)2 * Bn * K2c * 2); // [3][32][H] f32
constexpr size_t OFF_BAR = ALIGN256(OFF_CB + (size_t)3 * Bn * Hdim * 4); // barrier flags
constexpr size_t WS_NEED = OFF_BAR + 2048;

// gate-interleaved packed row: pr = u*64 + q*16 + rr  <->  orig row = q*1024 + u*16 + rr
__device__ __forceinline__ int orig_row(int pr) {
    int u = pr >> 6, q = (pr >> 4) & 3, rr = pr & 15;
    return q * Hdim + u * 16 + rr;
}

__device__ __forceinline__ float sigm(float x) { return 1.f / (1.f + __expf(-x)); }

__device__ __forceinline__ bf16x8 ld8(const bf16* p) {   // plain cached (weights)
    return *reinterpret_cast<const bf16x8*>(p);
}
// Coherent (agent-scope, relaxed) accessors for cross-block state.
// Per-location atomics need NO cache-wide maintenance (no buffer_inv) — the
// coherence bits on the individual load/store do the work; weights stay in L2.
__device__ __forceinline__ bf16x8 ld8c(const bf16* p) {  // 16B via 2x8B atomic loads
    union { unsigned long long u[2]; bf16x8 v; } x;
    x.u[0] = __hip_atomic_load((const unsigned long long*)p, __ATOMIC_RELAXED,
                               __HIP_MEMORY_SCOPE_AGENT);
    x.u[1] = __hip_atomic_load((const unsigned long long*)(p + 4), __ATOMIC_RELAXED,
                               __HIP_MEMORY_SCOPE_AGENT);
    return x.v;
}
__device__ __forceinline__ void st4c(bf16* p, unsigned v) {
    __hip_atomic_store((unsigned*)p, v, __ATOMIC_RELAXED, __HIP_MEMORY_SCOPE_AGENT);
}
__device__ __forceinline__ void st2c(bf16* p, unsigned short v) {
    __hip_atomic_store((unsigned short*)p, v, __ATOMIC_RELAXED, __HIP_MEMORY_SCOPE_AGENT);
}
__device__ __forceinline__ unsigned pack2bf(float a, float b) {
    union { bf16 h[2]; unsigned u; } x;
    x.h[0] = __float2bfloat16(a); x.h[1] = __float2bfloat16(b);
    return x.u;
}
__device__ __forceinline__ unsigned short bf16bits(float a) {
    union { bf16 h; unsigned short u; } x;
    x.h = __float2bfloat16(a);
    return x.u;
}
__device__ __forceinline__ f32x4 mfma16(bf16x8 a, bf16x8 b, f32x4 c) {
    return __builtin_amdgcn_mfma_f32_16x16x32_bf16(a, b, c, 0, 0, 0);
}

// ---------------- prep kernels ----------------
__global__ void k_pack_w1(const float* Wih, const float* Whh, bf16* dst) {
    const size_t n = (size_t)NG * K1p;
    for (size_t i = (size_t)blockIdx.x * blockDim.x + threadIdx.x; i < n;
         i += (size_t)gridDim.x * blockDim.x) {
        int pr = (int)(i / K1p), k = (int)(i % K1p);
        int ro = orig_row(pr);
        float v = 0.f;
        if (k < Fdim)                          v = Wih[(size_t)ro * Fdim + k];
        else if (k >= XPAD && k < XPAD + Hdim) v = Whh[(size_t)ro * Hdim + (k - XPAD)];
        dst[i] = __float2bfloat16(v);
    }
}

__global__ void k_pack_w23(const float* Wih, const float* Whh, bf16* dst) {
    const size_t n = (size_t)NG * K2c;
    for (size_t i = (size_t)blockIdx.x * blockDim.x + threadIdx.x; i < n;
         i += (size_t)gridDim.x * blockDim.x) {
        int pr = (int)(i / K2c), k = (int)(i % K2c);
        int ro = orig_row(pr);
        float v = (k < Hdim) ? Wih[(size_t)ro * Hdim + k]
                             : Whh[(size_t)ro * Hdim + (k - Hdim)];
        dst[i] = __float2bfloat16(v);
    }
}

__global__ void k_pack_wd(const float* Wd, bf16* dst) {
    const size_t n = (size_t)WDR * KDd;
    for (size_t i = (size_t)blockIdx.x * blockDim.x + threadIdx.x; i < n;
         i += (size_t)gridDim.x * blockDim.x) {
        int r = (int)(i / KDd), k = (int)(i % KDd);
        float v = (r < Fdim) ? Wd[(size_t)r * KDd + k] : 0.f;
        dst[i] = __float2bfloat16(v);
    }
}

__global__ void k_pack_bias(const float* bi1, const float* bh1,
                            const float* bi2, const float* bh2,
                            const float* bi3, const float* bh3,
                            const float* bd,
                            float* B1, float* B2, float* B3, float* BD) {
    const int n = 3 * NG + WDR;
    for (int i = blockIdx.x * blockDim.x + threadIdx.x; i < n;
         i += gridDim.x * blockDim.x) {
        if (i < NG)            { int ro = orig_row(i);        B1[i]        = bi1[ro] + bh1[ro]; }
        else if (i < 2 * NG)   { int ro = orig_row(i - NG);   B2[i - NG]   = bi2[ro] + bh2[ro]; }
        else if (i < 3 * NG)   { int ro = orig_row(i - 2*NG); B3[i - 2*NG] = bi3[ro] + bh3[ro]; }
        else { int r = i - 3 * NG; BD[r] = (r < Fdim) ? bd[r] : 0.f; }
    }
}

__global__ void k_init(const float* xseq, bf16* ab1, bf16* ab2, bf16* ab3,
                       float* cb, unsigned* bar, int T0) {
    const int n1 = 2 * Bn * K1p, n2 = 2 * Bn * K2c, n3 = 2 * Bn * K2c;
    const int nc = 3 * Bn * Hdim;
    const int tot = n1 + n2 + n3 + nc + 512;
    for (int i = blockIdx.x * blockDim.x + threadIdx.x; i < tot;
         i += gridDim.x * blockDim.x) {
        if (i < n1) {
            int buf = i / (Bn * K1p), rc = i % (Bn * K1p);
            int b = rc / K1p, c = rc % K1p;
            float v = 0.f;
            if (buf == 0 && c < Fdim) v = xseq[((size_t)b * T0 + 0) * Fdim + c];
            ab1[i] = __float2bfloat16(v);
        } else if (i < n1 + n2) {
            ab2[i - n1] = __float2bfloat16(0.f);
        } else if (i < n1 + n2 + n3) {
            ab3[i - n1 - n2] = __float2bfloat16(0.f);
        } else if (i < n1 + n2 + n3 + nc) {
            cb[i - n1 - n2 - n3] = 0.f;
        } else {
            bar[i - n1 - n2 - n3 - nc] = 0u;
        }
    }
}

__global__ void k_copy_orig(const float* xseq, float* out, int T, int T0) {
    const int n = Bn * T0 * Fdim;
    const size_t base = (size_t)Bn * T * Fdim;
    for (int i = blockIdx.x * blockDim.x + threadIdx.x; i < n;
         i += gridDim.x * blockDim.x) {
        out[base + i] = xseq[i];
    }
}

// ---------------- fence-free grid barriers ----------------
// __syncthreads() drains vmcnt for ALL waves before s_barrier (compiler emits
// the full waitcnt), and all cross-block data moves via agent-scope relaxed
// atomics (write-through to the coherence point) -> no fences, no buffer_inv,
// weights stay L2-resident. Arrival: one relaxed store to own flag slot.
// Everyone polls all flags directly (all-to-all; reads don't serialize).
__device__ __forceinline__ void gbar_all(unsigned* flags, unsigned target) {
    __syncthreads();
    const int tid = threadIdx.x;
    if (tid == 0)
        __hip_atomic_store(&flags[blockIdx.x], target, __ATOMIC_RELAXED,
                           __HIP_MEMORY_SCOPE_AGENT);
    if (tid < 64) {
        for (;;) {
            unsigned v0 = __hip_atomic_load(&flags[tid], __ATOMIC_RELAXED,
                                            __HIP_MEMORY_SCOPE_AGENT);
            unsigned v1 = __hip_atomic_load(&flags[tid + 64], __ATOMIC_RELAXED,
                                            __HIP_MEMORY_SCOPE_AGENT);
            unsigned v2 = __hip_atomic_load(&flags[tid + 128], __ATOMIC_RELAXED,
                                            __HIP_MEMORY_SCOPE_AGENT);
            if (__all(v0 >= target && v1 >= target && v2 >= target)) break;
            __builtin_amdgcn_s_sleep(1);
        }
    }
    asm volatile("" ::: "memory");
    __syncthreads();
}

// barrier over blocks 0..63 only (layer-1 + decoder feedback sync)
__device__ __forceinline__ void gbar64(unsigned* flags, unsigned target) {
    __syncthreads();
    const int tid = threadIdx.x;
    if (tid == 0)
        __hip_atomic_store(&flags[blockIdx.x], target, __ATOMIC_RELAXED,
                           __HIP_MEMORY_SCOPE_AGENT);
    if (tid < 64) {
        for (;;) {
            unsigned v = __hip_atomic_load(&flags[tid], __ATOMIC_RELAXED,
                                           __HIP_MEMORY_SCOPE_AGENT);
            if (__all(v >= target)) break;
            __builtin_amdgcn_s_sleep(1);
        }
    }
    asm volatile("" ::: "memory");
    __syncthreads();
}

// ---------------- phase-A gate GEMM (templated on K for register arrays) ----
// Preloads ALL A fragments for this wave's K-chunk first (fills the coherent-
// point latency once), then streams L2-resident weights.
template <int K>
__device__ __forceinline__ void gemmA(const bf16* __restrict__ Ar,
                                      const bf16* __restrict__ Wrow,
                                      float (&red)[4][32][65],
                                      int w, int lane) {
    constexpr int KQ = K / 4;
    constexpr int NF = KQ / 32;
    const int col = lane & 15;
    const int kb8 = (lane >> 4) << 3;
    const int k0 = w * KQ;

    bf16x8 a0[NF], a1[NF];
#pragma unroll
    for (int i = 0; i < NF; ++i) {
        a0[i] = ld8c(Ar + (size_t)col * K + k0 + i * 32 + kb8);
        a1[i] = ld8c(Ar + (size_t)(col + 16) * K + k0 + i * 32 + kb8);
    }
    f32x4 acc[2][4] = {};
#pragma unroll
    for (int i = 0; i < NF; ++i) {
        const bf16* wp = Wrow + (size_t)col * K + k0 + i * 32 + kb8;
#pragma unroll
        for (int q = 0; q < 4; ++q) {
            bf16x8 bq = ld8(wp + (size_t)q * 16 * K);
            acc[0][q] = mfma16(a0[i], bq, acc[0][q]);
            acc[1][q] = mfma16(a1[i], bq, acc[1][q]);
        }
    }
    __syncthreads();  // protect red[] from previous phase's readers
#pragma unroll
    for (int mt = 0; mt < 2; ++mt)
#pragma unroll
        for (int q = 0; q < 4; ++q)
#pragma unroll
            for (int r = 0; r < 4; ++r)
                red[w][mt * 16 + (lane >> 4) * 4 + r][q * 16 + col] = acc[mt][q][r];
    __syncthreads();
}

// ---------------- persistent LSTM kernel ----------------
// grid = NBLK x 256. block -> (layer = bid/64, unit-tile ut = bid%64).
// Phase A: gate GEMM (K split 4 ways over waves) + LDS reduce + c/h update.
//          Block 11 additionally stages the next conditioned input.
// barA (all 192 blocks), then phase B: blocks 0..10 decoder (+feedback when
// generative). barB (blocks 0..63 only) only on feedback steps — layer-2/3
// blocks' K=2048 GEMM overlaps the decoder+barB path.
__global__ __launch_bounds__(256, 1) void k_lstm(
    const float* __restrict__ xseq, float* __restrict__ out,
    const bf16* __restrict__ W1, const bf16* __restrict__ W2,
    const bf16* __restrict__ W3, const bf16* __restrict__ WD,
    const float* __restrict__ b1, const float* __restrict__ b2,
    const float* __restrict__ b3, const float* __restrict__ bdp,
    bf16* ab1, bf16* ab2, bf16* ab3, float* cb,
    unsigned* bar, int T0, int T) {
    __shared__ float red[4][32][65];

    const int tid = threadIdx.x;
    const int w = tid >> 6;
    const int lane = tid & 63;
    const int col = lane & 15;
    const int kb8 = (lane >> 4) << 3;
    const int bid = blockIdx.x;
    const int layer = bid >> 6;         // 0,1,2
    const int ut = bid & 63;            // hidden-unit tile (16 units)

    unsigned* flagsA = bar;             // [0..191]
    unsigned* flagsB = bar + 256;       // [0..63]

    const bf16* Wl = (layer == 0) ? W1 : (layer == 1) ? W2 : W3;
    const float* bl = (layer == 0) ? b1 : (layer == 1) ? b2 : b3;
    const int K = (layer == 0) ? K1p : K2c;
    bf16* abIn = (layer == 0) ? ab1 : (layer == 1) ? ab2 : ab3;

    // elementwise pair decomposition: thread -> (b, jj), jj even
    const int pair0 = tid * 2;
    const int eb = pair0 >> 4;
    const int ejj = pair0 & 15;

    for (int t = 0; t < T; ++t) {
        const int p = t & 1;

        // ---------- phase A: gate GEMM ----------
        {
            const bf16* Ar = abIn + (size_t)p * Bn * K;
            const bf16* Wrow = Wl + (size_t)(ut * 64) * K;
            if (layer == 0) gemmA<K1p>(Ar, Wrow, red, w, lane);
            else            gemmA<K2c>(Ar, Wrow, red, w, lane);

            // elementwise c/h update (2 consecutive jj per thread)
            bf16* ab1w = ab1 + (size_t)(p ^ 1) * Bn * K1p;
            bf16* ab2w = ab2 + (size_t)(p ^ 1) * Bn * K2c;
            bf16* ab3w = ab3 + (size_t)(p ^ 1) * Bn * K2c;
            float s0[4], s1[4];
#pragma unroll
            for (int q = 0; q < 4; ++q) {
                int c0 = q * 16 + ejj;
                s0[q] = red[0][eb][c0] + red[1][eb][c0] + red[2][eb][c0] +
                        red[3][eb][c0] + bl[ut * 64 + c0];
                s1[q] = red[0][eb][c0 + 1] + red[1][eb][c0 + 1] + red[2][eb][c0 + 1] +
                        red[3][eb][c0 + 1] + bl[ut * 64 + c0 + 1];
            }
            int j = ut * 16 + ejj;
            size_t cidx = ((size_t)layer * Bn + eb) * Hdim + j;
            float2 cold = *reinterpret_cast<float2*>(&cb[cidx]);
            float cn0 = sigm(s0[1]) * cold.x + sigm(s0[0]) * tanhf(s0[2]);
            float hn0 = sigm(s0[3]) * tanhf(cn0);
            float cn1 = sigm(s1[1]) * cold.y + sigm(s1[0]) * tanhf(s1[2]);
            float hn1 = sigm(s1[3]) * tanhf(cn1);
            *reinterpret_cast<float2*>(&cb[cidx]) = make_float2(cn0, cn1);
            unsigned hp = pack2bf(hn0, hn1);
            if (layer == 0) {
                st4c(&ab1w[(size_t)eb * K1p + XPAD + j], hp);
                st4c(&ab2w[(size_t)eb * K2c + j], hp);
            } else if (layer == 1) {
                st4c(&ab2w[(size_t)eb * K2c + Hdim + j], hp);
                st4c(&ab3w[(size_t)eb * K2c + j], hp);
            } else {
                st4c(&ab3w[(size_t)eb * K2c + Hdim + j], hp);
            }

            // stage conditioned input x(t+1) (independent of everything else)
            if (bid == 11 && t + 1 < T0) {
                bf16* dst = ab1 + (size_t)(p ^ 1) * Bn * K1p;
                for (int i = tid; i < Bn * 86; i += 256) {
                    int b = i / 86, f0 = (i % 86) * 2;
                    const float* sp = xseq + ((size_t)b * T0 + (t + 1)) * Fdim;
                    if (f0 + 1 < Fdim)
                        st4c(&dst[(size_t)b * K1p + f0], pack2bf(sp[f0], sp[f0 + 1]));
                    else
                        st2c(&dst[(size_t)b * K1p + f0], bf16bits(sp[f0]));
                }
            }
        }
        gbar_all(flagsA, (unsigned)(t + 1));

        // ---------- phase B: decoder (+feedback) ----------
        if (bid < 11) {
            const bf16* Ad = ab3 + (size_t)(p ^ 1) * Bn * K2c + Hdim;
            const bf16* Wrowd = WD + (size_t)(bid * 16) * KDd;
            constexpr int NFD = 8;          // (1024/4)/32
            const int dk0 = w * 256;
            bf16x8 da0[NFD], da1[NFD];
#pragma unroll
            for (int i = 0; i < NFD; ++i) {
                da0[i] = ld8c(Ad + (size_t)col * K2c + dk0 + i * 32 + kb8);
                da1[i] = ld8c(Ad + (size_t)(col + 16) * K2c + dk0 + i * 32 + kb8);
            }
            f32x4 dacc[2] = {};
#pragma unroll
            for (int i = 0; i < NFD; ++i) {
                bf16x8 bq = ld8(Wrowd + (size_t)col * KDd + dk0 + i * 32 + kb8);
                dacc[0] = mfma16(da0[i], bq, dacc[0]);
                dacc[1] = mfma16(da1[i], bq, dacc[1]);
            }
            __syncthreads();
#pragma unroll
            for (int mt = 0; mt < 2; ++mt)
#pragma unroll
                for (int r = 0; r < 4; ++r)
                    red[w][mt * 16 + (lane >> 4) * 4 + r][col] = dacc[mt][r];
            __syncthreads();
            {
                int f0 = bid * 16 + ejj;
                float v0 = red[0][eb][ejj] + red[1][eb][ejj] + red[2][eb][ejj] +
                           red[3][eb][ejj] + bdp[f0];
                float v1 = red[0][eb][ejj + 1] + red[1][eb][ejj + 1] +
                           red[2][eb][ejj + 1] + red[3][eb][ejj + 1] + bdp[f0 + 1];
                float* orow = out + (size_t)eb * ((size_t)T * Fdim) + (size_t)t * Fdim;
                if (f0 < Fdim)     orow[f0] = v0;
                if (f0 + 1 < Fdim) orow[f0 + 1] = v1;
                if (t >= T0 - 1) {  // out(t) = x(t+1) in the generative phase
                    bf16* fbw = ab1 + (size_t)(p ^ 1) * Bn * K1p + (size_t)eb * K1p;
                    if (f0 + 1 < Fdim)      st4c(&fbw[f0], pack2bf(v0, v1));
                    else if (f0 < Fdim)     st2c(&fbw[f0], bf16bits(v0));
                }
            }
        }
        if (t >= T0 - 1 && bid < 64)
            gbar64(flagsB, (unsigned)(t - T0 + 2));
    }
}

// ---------------- host launch ----------------
extern "C" void kernel_launch(void* const* d_in, const int* in_sizes, int n_in,
                              void* d_out, int out_size, void* d_ws, size_t ws_size,
                              hipStream_t stream) {
    const float* xseq = (const float*)d_in[0];
    const float* Wih1 = (const float*)d_in[2];
    const float* Whh1 = (const float*)d_in[3];
    const float* bih1 = (const float*)d_in[4];
    const float* bhh1 = (const float*)d_in[5];
    const float* Wih2 = (const float*)d_in[6];
    const float* Whh2 = (const float*)d_in[7];
    const float* bih2 = (const float*)d_in[8];
    const float* bhh2 = (const float*)d_in[9];
    const float* Wih3 = (const float*)d_in[10];
    const float* Whh3 = (const float*)d_in[11];
    const float* bih3 = (const float*)d_in[12];
    const float* bhh3 = (const float*)d_in[13];
    const float* Wd   = (const float*)d_in[14];
    const float* bd   = (const float*)d_in[15];

    const int T0 = in_sizes[0] / (Bn * Fdim);                 // 50
    const int T  = out_size / (Bn * Fdim) - T0;               // 350

    char* ws = (char*)d_ws;
    bf16*  pW1 = (bf16*)(ws + OFF_W1);
    bf16*  pW2 = (bf16*)(ws + OFF_W2);
    bf16*  pW3 = (bf16*)(ws + OFF_W3);
    bf16*  pWD = (bf16*)(ws + OFF_WD);
    float* pB1 = (float*)(ws + OFF_B1);
    float* pB2 = (float*)(ws + OFF_B2);
    float* pB3 = (float*)(ws + OFF_B3);
    float* pBD = (float*)(ws + OFF_BD);
    bf16*  ab1 = (bf16*)(ws + OFF_AB1);
    bf16*  ab2 = (bf16*)(ws + OFF_AB2);
    bf16*  ab3 = (bf16*)(ws + OFF_AB3);
    float* cbp = (float*)(ws + OFF_CB);
    unsigned* bar = (unsigned*)(ws + OFF_BAR);
    float* out = (float*)d_out;

    (void)ws_size; (void)n_in;  // WS_NEED ~= 45.6 MB

    hipLaunchKernelGGL(k_pack_w1, dim3(1024), dim3(256), 0, stream, Wih1, Whh1, pW1);
    hipLaunchKernelGGL(k_pack_w23, dim3(1024), dim3(256), 0, stream, Wih2, Whh2, pW2);
    hipLaunchKernelGGL(k_pack_w23, dim3(1024), dim3(256), 0, stream, Wih3, Whh3, pW3);
    hipLaunchKernelGGL(k_pack_wd, dim3(704), dim3(256), 0, stream, Wd, pWD);
    hipLaunchKernelGGL(k_pack_bias, dim3(49), dim3(256), 0, stream,
                       bih1, bhh1, bih2, bhh2, bih3, bhh3, bd, pB1, pB2, pB3, pBD);
    hipLaunchKernelGGL(k_init, dim3(1024), dim3(256), 0, stream,
                       xseq, ab1, ab2, ab3, cbp, bar, T0);
    hipLaunchKernelGGL(k_lstm, dim3(NBLK), dim3(256), 0, stream,
                       xseq, out, pW1, pW2, pW3, pWD, pB1, pB2, pB3, pBD,
                       ab1, ab2, ab3, cbp, bar, T0, T);
    hipLaunchKernelGGL(k_copy_orig, dim3(1069), dim3(256), 0, stream, xseq, out, T, T0);
}

// Round 4
// 5635.319 us; speedup vs baseline: 2.5977x; 1.6554x over previous
//
#include <hip/hip_runtime.h>
#include <hip/hip_bf16.h>

// Problem constants (fixed by the bench: B=32, T0=50, F=171, H=1024, G=300)
#define Bn   32
#define Fdim 171
#define XPAD 176             // x-region padded to 11 tiles of 16
#define Hdim 1024
#define NG   4096            // 4*H gate rows
#define K1p  1280            // layer1 K = XPAD+H = 1200, padded to 1280 (80 tiles)
#define K2c  2048            // layer2/3 K = 2H (128 tiles)
#define KDd  1024            // decoder K = H
#define WDR  176             // decoder rows padded 171 -> 176
#define NBLK 192             // persistent grid: 3 layers x 64 unit-tiles
#define S1e  (80 * 512)      // ab1 slot elements (tiled [80][32][16])
#define S2e  (128 * 512)     // ab2/ab3 slot elements (tiled [128][32][16])

typedef __attribute__((ext_vector_type(8))) short bf16x8;
typedef __attribute__((ext_vector_type(4))) float f32x4;
typedef __hip_bfloat16 bf16;

// ---------------- static workspace layout (bytes); ab buffers are tail ----
#define ALIGN256(x) ((((size_t)(x)) + 255) & ~(size_t)255)
constexpr size_t OFF_W1  = 0;
constexpr size_t OFF_W2  = ALIGN256(OFF_W1 + (size_t)NG * K1p * 2);
constexpr size_t OFF_W3  = ALIGN256(OFF_W2 + (size_t)NG * K2c * 2);
constexpr size_t OFF_WD  = ALIGN256(OFF_W3 + (size_t)NG * K2c * 2);
constexpr size_t OFF_B1  = ALIGN256(OFF_WD + (size_t)WDR * KDd * 2);
constexpr size_t OFF_B2  = ALIGN256(OFF_B1 + (size_t)NG * 4);
constexpr size_t OFF_B3  = ALIGN256(OFF_B2 + (size_t)NG * 4);
constexpr size_t OFF_BD  = ALIGN256(OFF_B3 + (size_t)NG * 4);
constexpr size_t OFF_CB  = ALIGN256(OFF_BD + (size_t)WDR * 4);
constexpr size_t OFF_BAR = ALIGN256(OFF_CB + (size_t)3 * Bn * Hdim * 4);
constexpr size_t OFF_AB1 = ALIGN256(OFF_BAR + 2048);
// ab1: D*S1e*2; ab2: D*S2e*2; ab3: D*S2e*2  (D chosen from ws_size; <=32)

// gate-interleaved packed row: pr = u*64 + q*16 + rr  <->  orig row = q*1024 + u*16 + rr
__device__ __forceinline__ int orig_row(int pr) {
    int u = pr >> 6, q = (pr >> 4) & 3, rr = pr & 15;
    return q * Hdim + u * 16 + rr;
}

__device__ __forceinline__ float sigm(float x) { return 1.f / (1.f + __expf(-x)); }

__device__ __forceinline__ bf16x8 ld8(const bf16* p) {   // plain cached load
    return *reinterpret_cast<const bf16x8*>(p);
}
// Coherent write-through stores (agent scope, relaxed): reach the coherence
// point, no cache-wide maintenance; readers use plain cached loads + rotation.
__device__ __forceinline__ void st2c(bf16* p, unsigned short v) {
    __hip_atomic_store((unsigned short*)p, v, __ATOMIC_RELAXED, __HIP_MEMORY_SCOPE_AGENT);
}
__device__ __forceinline__ void stu64(unsigned long long* p, unsigned long long v) {
    __hip_atomic_store(p, v, __ATOMIC_RELAXED, __HIP_MEMORY_SCOPE_AGENT);
}
__device__ __forceinline__ unsigned short bf16bits(float a) {
    union { bf16 h; unsigned short u; } x;
    x.h = __float2bfloat16(a);
    return x.u;
}
__device__ __forceinline__ f32x4 mfma16(bf16x8 a, bf16x8 b, f32x4 c) {
    return __builtin_amdgcn_mfma_f32_16x16x32_bf16(a, b, c, 0, 0, 0);
}

// ---------------- prep kernels ----------------
__global__ void k_pack_w1(const float* Wih, const float* Whh, bf16* dst) {
    const size_t n = (size_t)NG * K1p;
    for (size_t i = (size_t)blockIdx.x * blockDim.x + threadIdx.x; i < n;
         i += (size_t)gridDim.x * blockDim.x) {
        int pr = (int)(i / K1p), k = (int)(i % K1p);
        int ro = orig_row(pr);
        float v = 0.f;
        if (k < Fdim)                          v = Wih[(size_t)ro * Fdim + k];
        else if (k >= XPAD && k < XPAD + Hdim) v = Whh[(size_t)ro * Hdim + (k - XPAD)];
        dst[i] = __float2bfloat16(v);
    }
}

__global__ void k_pack_w23(const float* Wih, const float* Whh, bf16* dst) {
    const size_t n = (size_t)NG * K2c;
    for (size_t i = (size_t)blockIdx.x * blockDim.x + threadIdx.x; i < n;
         i += (size_t)gridDim.x * blockDim.x) {
        int pr = (int)(i / K2c), k = (int)(i % K2c);
        int ro = orig_row(pr);
        float v = (k < Hdim) ? Wih[(size_t)ro * Hdim + k]
                             : Whh[(size_t)ro * Hdim + (k - Hdim)];
        dst[i] = __float2bfloat16(v);
    }
}

__global__ void k_pack_wd(const float* Wd, bf16* dst) {
    const size_t n = (size_t)WDR * KDd;
    for (size_t i = (size_t)blockIdx.x * blockDim.x + threadIdx.x; i < n;
         i += (size_t)gridDim.x * blockDim.x) {
        int r = (int)(i / KDd), k = (int)(i % KDd);
        float v = (r < Fdim) ? Wd[(size_t)r * KDd + k] : 0.f;
        dst[i] = __float2bfloat16(v);
    }
}

__global__ void k_pack_bias(const float* bi1, const float* bh1,
                            const float* bi2, const float* bh2,
                            const float* bi3, const float* bh3,
                            const float* bd,
                            float* B1, float* B2, float* B3, float* BD) {
    const int n = 3 * NG + WDR;
    for (int i = blockIdx.x * blockDim.x + threadIdx.x; i < n;
         i += gridDim.x * blockDim.x) {
        if (i < NG)            { int ro = orig_row(i);        B1[i]        = bi1[ro] + bh1[ro]; }
        else if (i < 2 * NG)   { int ro = orig_row(i - NG);   B2[i - NG]   = bi2[ro] + bh2[ro]; }
        else if (i < 3 * NG)   { int ro = orig_row(i - 2*NG); B3[i - 2*NG] = bi3[ro] + bh3[ro]; }
        else { int r = i - 3 * NG; BD[r] = (r < Fdim) ? bd[r] : 0.f; }
    }
}

// zero all rotating state slots with coherent stores (no cached copies anywhere)
__global__ void k_init(bf16* ab1, bf16* ab2, bf16* ab3, float* cb, unsigned* bar, int D) {
    const size_t n1 = (size_t)D * (S1e / 4);   // u64 count
    const size_t n2 = (size_t)D * (S2e / 4);
    const size_t nc = 3 * Bn * Hdim;
    const size_t tot = n1 + 2 * n2 + nc + 512;
    for (size_t i = (size_t)blockIdx.x * blockDim.x + threadIdx.x; i < tot;
         i += (size_t)gridDim.x * blockDim.x) {
        if (i < n1)            stu64((unsigned long long*)ab1 + i, 0ull);
        else if (i < n1 + n2)  stu64((unsigned long long*)ab2 + (i - n1), 0ull);
        else if (i < n1 + 2*n2) stu64((unsigned long long*)ab3 + (i - n1 - n2), 0ull);
        else if (i < n1 + 2*n2 + nc) cb[i - n1 - 2*n2] = 0.f;
        else bar[i - n1 - 2*n2 - nc] = 0u;
    }
}

// stage x(0) into slot 0 (tiled layout), coherent
__global__ void k_stage0(const float* xseq, bf16* ab1, int T0) {
    for (int idx = blockIdx.x * blockDim.x + threadIdx.x; idx < Bn * 11 * 16;
         idx += gridDim.x * blockDim.x) {
        int fu = idx >> 9, rem = idx & 511, b = rem >> 4, jj = rem & 15;
        int f = fu * 16 + jj;
        if (f < Fdim)
            st2c(&ab1[idx], bf16bits(xseq[(size_t)b * T0 * Fdim + f]));
    }
}

__global__ void k_copy_orig(const float* xseq, float* out, int T, int T0) {
    const int n = Bn * T0 * Fdim;
    const size_t base = (size_t)Bn * T * Fdim;
    for (int i = blockIdx.x * blockDim.x + threadIdx.x; i < n;
         i += gridDim.x * blockDim.x) {
        out[base + i] = xseq[i];
    }
}

// ---------------- fence-free grid barriers (flag array, relaxed atomics) ----
__device__ __forceinline__ void gbar_all(unsigned* flags, unsigned target) {
    __syncthreads();   // drains vmcnt: all state stores acked before flag
    const int tid = threadIdx.x;
    if (tid == 0)
        __hip_atomic_store(&flags[blockIdx.x], target, __ATOMIC_RELAXED,
                           __HIP_MEMORY_SCOPE_AGENT);
    if (tid < 64) {
        for (;;) {
            unsigned v0 = __hip_atomic_load(&flags[tid], __ATOMIC_RELAXED,
                                            __HIP_MEMORY_SCOPE_AGENT);
            unsigned v1 = __hip_atomic_load(&flags[tid + 64], __ATOMIC_RELAXED,
                                            __HIP_MEMORY_SCOPE_AGENT);
            unsigned v2 = __hip_atomic_load(&flags[tid + 128], __ATOMIC_RELAXED,
                                            __HIP_MEMORY_SCOPE_AGENT);
            if (__all(v0 >= target && v1 >= target && v2 >= target)) break;
            __builtin_amdgcn_s_sleep(1);
        }
    }
    asm volatile("" ::: "memory");
    __syncthreads();
}

__device__ __forceinline__ void gbar64(unsigned* flags, unsigned target) {
    __syncthreads();
    const int tid = threadIdx.x;
    if (tid == 0)
        __hip_atomic_store(&flags[blockIdx.x], target, __ATOMIC_RELAXED,
                           __HIP_MEMORY_SCOPE_AGENT);
    if (tid < 64) {
        for (;;) {
            unsigned v = __hip_atomic_load(&flags[tid], __ATOMIC_RELAXED,
                                           __HIP_MEMORY_SCOPE_AGENT);
            if (__all(v >= target)) break;
            __builtin_amdgcn_s_sleep(1);
        }
    }
    asm volatile("" ::: "memory");
    __syncthreads();
}

// ---------------- phase-A gate GEMM ----------------
// State A is tiled [k/16][b][16]; weights are row-linear [gate_row][k].
// 8 waves split K 8 ways; plain cached loads everywhere.
template <int K, int NF>
__device__ __forceinline__ void gemmA(const bf16* __restrict__ As,
                                      const bf16* __restrict__ Wrow,
                                      float (&red)[8][32][66],
                                      int w, int lane) {
    const int col = lane & 15;
    const int kb8 = (lane >> 4) << 3;
    const int k0 = w * (K / 8);

    bf16x8 a0[NF], a1[NF];
#pragma unroll
    for (int i = 0; i < NF; ++i) {
        int k = k0 + i * 32 + kb8;
        const bf16* ap = As + (size_t)((k >> 4) * Bn) * 16 + (k & 15);
        a0[i] = ld8(ap + col * 16);
        a1[i] = ld8(ap + (col + 16) * 16);
    }
    f32x4 acc[2][4] = {};
#pragma unroll
    for (int i = 0; i < NF; ++i) {
        const bf16* wp = Wrow + (size_t)col * K + k0 + i * 32 + kb8;
#pragma unroll
        for (int q = 0; q < 4; ++q) {
            bf16x8 bq = ld8(wp + (size_t)q * 16 * K);
            acc[0][q] = mfma16(a0[i], bq, acc[0][q]);
            acc[1][q] = mfma16(a1[i], bq, acc[1][q]);
        }
    }
    __syncthreads();  // protect red[] from previous phase's readers
#pragma unroll
    for (int mt = 0; mt < 2; ++mt)
#pragma unroll
        for (int q = 0; q < 4; ++q)
#pragma unroll
            for (int r = 0; r < 4; ++r)
                red[w][mt * 16 + (lane >> 4) * 4 + r][q * 16 + col] = acc[mt][q][r];
    __syncthreads();
}

// ---------------- persistent LSTM kernel ----------------
// grid = 192 x 512 threads (8 waves). block -> (layer = bid/64, ut = bid%64).
// Rotating state slots (D deep): step t reads slot t&dm, writes slot (t+1)&dm.
__global__ __launch_bounds__(512, 1) void k_lstm(
    const float* __restrict__ xseq, float* __restrict__ out,
    const bf16* __restrict__ W1, const bf16* __restrict__ W2,
    const bf16* __restrict__ W3, const bf16* __restrict__ WD,
    const float* __restrict__ b1, const float* __restrict__ b2,
    const float* __restrict__ b3, const float* __restrict__ bdp,
    bf16* ab1, bf16* ab2, bf16* ab3, float* cb,
    unsigned* bar, int T0, int T, int dm) {
    __shared__ float red[8][32][66];

    const int tid = threadIdx.x;
    const int w = tid >> 6;
    const int lane = tid & 63;
    const int col = lane & 15;
    const int kb8 = (lane >> 4) << 3;
    const int bid = blockIdx.x;
    const int layer = bid >> 6;
    const int ut = bid & 63;

    unsigned* flagsA = bar;
    unsigned* flagsB = bar + 256;

    const bf16* Wl = (layer == 0) ? W1 : (layer == 1) ? W2 : W3;
    const float* bl = (layer == 0) ? b1 : (layer == 1) ? b2 : b3;
    bf16* abIn = (layer == 0) ? ab1 : (layer == 1) ? ab2 : ab3;
    const size_t Sl = (layer == 0) ? (size_t)S1e : (size_t)S2e;
    const int Kl = (layer == 0) ? K1p : K2c;

    const int eb = tid >> 4;      // elementwise batch row
    const int ejj = tid & 15;     // elementwise unit-within-tile

    for (int t = 0; t < T; ++t) {
        const int st = t & dm;
        const int ns = (t + 1) & dm;

        // ---------- phase A: gate GEMM + state update ----------
        {
            const bf16* As = abIn + (size_t)st * Sl;
            const bf16* Wrow = Wl + (size_t)(ut * 64) * Kl;
            if (layer == 0) gemmA<K1p, 5>(As, Wrow, red, w, lane);
            else            gemmA<K2c, 8>(As, Wrow, red, w, lane);

            float s[4];
#pragma unroll
            for (int q = 0; q < 4; ++q) {
                float a = bl[ut * 64 + q * 16 + ejj];
#pragma unroll
                for (int ww = 0; ww < 8; ++ww) a += red[ww][eb][q * 16 + ejj];
                s[q] = a;
            }
            size_t cidx = ((size_t)layer * Bn + eb) * Hdim + ut * 16 + ejj;
            float cold = cb[cidx];
            float cn = sigm(s[1]) * cold + sigm(s[0]) * tanhf(s[2]);
            float hn = sigm(s[3]) * tanhf(cn);
            cb[cidx] = cn;
            unsigned short hb = bf16bits(hn);
            const int off = eb * 16 + ejj;
            if (layer == 0) {
                st2c(ab1 + (size_t)ns * S1e + (11 + ut) * 512 + off, hb);
                st2c(ab2 + (size_t)ns * S2e + ut * 512 + off, hb);
            } else if (layer == 1) {
                st2c(ab2 + (size_t)ns * S2e + (64 + ut) * 512 + off, hb);
                st2c(ab3 + (size_t)ns * S2e + ut * 512 + off, hb);
            } else {
                st2c(ab3 + (size_t)ns * S2e + (64 + ut) * 512 + off, hb);
            }

            if (bid == 11 && t + 1 < T0) {  // stage conditioned x(t+1), tiled
                bf16* dst = ab1 + (size_t)ns * S1e;
                for (int idx = tid; idx < Bn * 11 * 16; idx += 512) {
                    int fu = idx >> 9, rem = idx & 511, b = rem >> 4, jj = rem & 15;
                    int f = fu * 16 + jj;
                    if (f < Fdim)
                        st2c(dst + idx,
                             bf16bits(xseq[((size_t)b * T0 + t + 1) * Fdim + f]));
                }
            }
        }
        gbar_all(flagsA, (unsigned)(t + 1));

        // ---------- phase B: decoder (+feedback) ----------
        if (bid < 11) {
            const bf16* As = ab3 + (size_t)ns * S2e + 64 * 512;  // h2 tiles
            const bf16* Wrowd = WD + (size_t)(bid * 16) * KDd;
            const int dk0 = w * 128;
            bf16x8 da0[4], da1[4];
#pragma unroll
            for (int i = 0; i < 4; ++i) {
                int k = dk0 + i * 32 + kb8;
                const bf16* ap = As + (size_t)((k >> 4) * Bn) * 16 + (k & 15);
                da0[i] = ld8(ap + col * 16);
                da1[i] = ld8(ap + (col + 16) * 16);
            }
            f32x4 dacc[2] = {};
#pragma unroll
            for (int i = 0; i < 4; ++i) {
                bf16x8 bq = ld8(Wrowd + (size_t)col * KDd + dk0 + i * 32 + kb8);
                dacc[0] = mfma16(da0[i], bq, dacc[0]);
                dacc[1] = mfma16(da1[i], bq, dacc[1]);
            }
            __syncthreads();
#pragma unroll
            for (int mt = 0; mt < 2; ++mt)
#pragma unroll
                for (int r = 0; r < 4; ++r)
                    red[w][mt * 16 + (lane >> 4) * 4 + r][col] = dacc[mt][r];
            __syncthreads();
            {
                int f = bid * 16 + ejj;
                float v = bdp[f];
#pragma unroll
                for (int ww = 0; ww < 8; ++ww) v += red[ww][eb][ejj];
                if (f < Fdim) {
                    out[(size_t)eb * ((size_t)T * Fdim) + (size_t)t * Fdim + f] = v;
                    if (t >= T0 - 1)  // out(t) = x(t+1) in the generative phase
                        st2c(ab1 + (size_t)ns * S1e + bid * 512 + eb * 16 + ejj,
                             bf16bits(v));
                }
            }
        }
        if (t >= T0 - 1 && bid < 64)
            gbar64(flagsB, (unsigned)(t - T0 + 2));
    }
}

// ---------------- host launch ----------------
extern "C" void kernel_launch(void* const* d_in, const int* in_sizes, int n_in,
                              void* d_out, int out_size, void* d_ws, size_t ws_size,
                              hipStream_t stream) {
    const float* xseq = (const float*)d_in[0];
    const float* Wih1 = (const float*)d_in[2];
    const float* Whh1 = (const float*)d_in[3];
    const float* bih1 = (const float*)d_in[4];
    const float* bhh1 = (const float*)d_in[5];
    const float* Wih2 = (const float*)d_in[6];
    const float* Whh2 = (const float*)d_in[7];
    const float* bih2 = (const float*)d_in[8];
    const float* bhh2 = (const float*)d_in[9];
    const float* Wih3 = (const float*)d_in[10];
    const float* Whh3 = (const float*)d_in[11];
    const float* bih3 = (const float*)d_in[12];
    const float* bhh3 = (const float*)d_in[13];
    const float* Wd   = (const float*)d_in[14];
    const float* bd   = (const float*)d_in[15];

    const int T0 = in_sizes[0] / (Bn * Fdim);                 // 50
    const int T  = out_size / (Bn * Fdim) - T0;               // 350

    char* ws = (char*)d_ws;
    bf16*  pW1 = (bf16*)(ws + OFF_W1);
    bf16*  pW2 = (bf16*)(ws + OFF_W2);
    bf16*  pW3 = (bf16*)(ws + OFF_W3);
    bf16*  pWD = (bf16*)(ws + OFF_WD);
    float* pB1 = (float*)(ws + OFF_B1);
    float* pB2 = (float*)(ws + OFF_B2);
    float* pB3 = (float*)(ws + OFF_B3);
    float* pBD = (float*)(ws + OFF_BD);
    float* cbp = (float*)(ws + OFF_CB);
    unsigned* bar = (unsigned*)(ws + OFF_BAR);
    float* out = (float*)d_out;

    // rotation depth: largest power-of-2 D (<=32) whose state fits in ws
    int D = 32;
    while (D > 4 &&
           OFF_AB1 + (size_t)D * ((size_t)S1e + 2 * (size_t)S2e) * 2 > ws_size)
        D >>= 1;
    bf16* ab1 = (bf16*)(ws + OFF_AB1);
    bf16* ab2 = ab1 + (size_t)D * S1e;
    bf16* ab3 = ab2 + (size_t)D * S2e;

    (void)n_in;  // total need @D=32 ~= 55.9 MB

    hipLaunchKernelGGL(k_pack_w1, dim3(1024), dim3(256), 0, stream, Wih1, Whh1, pW1);
    hipLaunchKernelGGL(k_pack_w23, dim3(1024), dim3(256), 0, stream, Wih2, Whh2, pW2);
    hipLaunchKernelGGL(k_pack_w23, dim3(1024), dim3(256), 0, stream, Wih3, Whh3, pW3);
    hipLaunchKernelGGL(k_pack_wd, dim3(704), dim3(256), 0, stream, Wd, pWD);
    hipLaunchKernelGGL(k_pack_bias, dim3(49), dim3(256), 0, stream,
                       bih1, bhh1, bih2, bhh2, bih3, bhh3, bd, pB1, pB2, pB3, pBD);
    hipLaunchKernelGGL(k_init, dim3(2048), dim3(256), 0, stream,
                       ab1, ab2, ab3, cbp, bar, D);
    hipLaunchKernelGGL(k_stage0, dim3(22), dim3(256), 0, stream, xseq, ab1, T0);
    hipLaunchKernelGGL(k_lstm, dim3(NBLK), dim3(512), 0, stream,
                       xseq, out, pW1, pW2, pW3, pWD, pB1, pB2, pB3, pBD,
                       ab1, ab2, ab3, cbp, bar, T0, T, D - 1);
    hipLaunchKernelGGL(k_copy_orig, dim3(1069), dim3(256), 0, stream, xseq, out, T, T0);
}

// Round 5
// 4913.717 us; speedup vs baseline: 2.9792x; 1.1469x over previous
//
#include <hip/hip_runtime.h>
#include <hip/hip_bf16.h>
#include <hip/hip_fp8.h>

// Problem constants (fixed by the bench: B=32, T0=50, F=171, H=1024, G=300)
#define Bn   32
#define Fdim 171
#define XPAD 176             // x-region padded to 11 tiles of 16
#define Hdim 1024
#define NG   4096            // 4*H gate rows
#define K1p  1280            // layer1 K = XPAD+H = 1200, padded to 1280 (80 tiles)
#define K2c  2048            // layer2/3 K = 2H (128 tiles)
#define KDd  1024            // decoder K = H
#define WDR  176             // decoder rows padded 171 -> 176
#define NBLK 192             // persistent grid: 3 layers x 64 unit-tiles
#define S1e  (80 * 512)      // ab1 slot BYTES (fp8, tiled [80][32][16])
#define S2e  (128 * 512)     // ab2/ab3 slot BYTES (tiled [128][32][16])

// fp8 scaling: weights *64, activations *16, both exact powers of 2.
#define SW    64.0f
#define SA    16.0f
#define INVS  (1.0f / (SW * SA))

typedef __attribute__((ext_vector_type(4))) float f32x4;
typedef __hip_bfloat16 bf16;
typedef unsigned char fp8;

// ---------------- static workspace layout (bytes); ab buffers are tail ----
#define ALIGN256(x) ((((size_t)(x)) + 255) & ~(size_t)255)
constexpr size_t OFF_W1  = 0;
constexpr size_t OFF_W2  = ALIGN256(OFF_W1 + (size_t)NG * K1p);
constexpr size_t OFF_W3  = ALIGN256(OFF_W2 + (size_t)NG * K2c);
constexpr size_t OFF_WD  = ALIGN256(OFF_W3 + (size_t)NG * K2c);
constexpr size_t OFF_B1  = ALIGN256(OFF_WD + (size_t)WDR * KDd);
constexpr size_t OFF_B2  = ALIGN256(OFF_B1 + (size_t)NG * 4);
constexpr size_t OFF_B3  = ALIGN256(OFF_B2 + (size_t)NG * 4);
constexpr size_t OFF_BD  = ALIGN256(OFF_B3 + (size_t)NG * 4);
constexpr size_t OFF_CB  = ALIGN256(OFF_BD + (size_t)WDR * 4);
constexpr size_t OFF_BAR = ALIGN256(OFF_CB + (size_t)3 * Bn * Hdim * 4);
constexpr size_t OFF_AB1 = ALIGN256(OFF_BAR + 2048);
// ab1: D*S1e; ab2: D*S2e; ab3: D*S2e  (D chosen from ws_size; <=32)

// gate-interleaved packed row: pr = u*64 + q*16 + rr  <->  orig row = q*1024 + u*16 + rr
__device__ __forceinline__ int orig_row(int pr) {
    int u = pr >> 6, q = (pr >> 4) & 3, rr = pr & 15;
    return q * Hdim + u * 16 + rr;
}

__device__ __forceinline__ float sigm(float x) { return 1.f / (1.f + __expf(-x)); }

__device__ __forceinline__ unsigned char f2fp8(float x) {  // OCP e4m3, RNE+sat
    __hip_fp8_e4m3 q(x);
    return (unsigned char)q.__x;
}

__device__ __forceinline__ long ld8b(const fp8* p) {   // plain cached 8B load
    return *reinterpret_cast<const long*>(p);
}
// Coherent write-through stores (agent scope, relaxed): reach the coherence
// point, no cache-wide maintenance; readers use plain cached loads + rotation.
__device__ __forceinline__ void st1c(fp8* p, unsigned char v) {
    __hip_atomic_store((unsigned char*)p, v, __ATOMIC_RELAXED, __HIP_MEMORY_SCOPE_AGENT);
}
__device__ __forceinline__ void stu64(unsigned long long* p, unsigned long long v) {
    __hip_atomic_store(p, v, __ATOMIC_RELAXED, __HIP_MEMORY_SCOPE_AGENT);
}
__device__ __forceinline__ f32x4 mfma8(long a, long b, f32x4 c) {
    return __builtin_amdgcn_mfma_f32_16x16x32_fp8_fp8(a, b, c, 0, 0, 0);
}

// ---------------- prep kernels ----------------
__global__ void k_pack_w1(const float* Wih, const float* Whh, fp8* dst) {
    const size_t n = (size_t)NG * K1p;
    for (size_t i = (size_t)blockIdx.x * blockDim.x + threadIdx.x; i < n;
         i += (size_t)gridDim.x * blockDim.x) {
        int pr = (int)(i / K1p), k = (int)(i % K1p);
        int ro = orig_row(pr);
        float v = 0.f;
        if (k < Fdim)                          v = Wih[(size_t)ro * Fdim + k];
        else if (k >= XPAD && k < XPAD + Hdim) v = Whh[(size_t)ro * Hdim + (k - XPAD)];
        dst[i] = f2fp8(v * SW);
    }
}

__global__ void k_pack_w23(const float* Wih, const float* Whh, fp8* dst) {
    const size_t n = (size_t)NG * K2c;
    for (size_t i = (size_t)blockIdx.x * blockDim.x + threadIdx.x; i < n;
         i += (size_t)gridDim.x * blockDim.x) {
        int pr = (int)(i / K2c), k = (int)(i % K2c);
        int ro = orig_row(pr);
        float v = (k < Hdim) ? Wih[(size_t)ro * Hdim + k]
                             : Whh[(size_t)ro * Hdim + (k - Hdim)];
        dst[i] = f2fp8(v * SW);
    }
}

__global__ void k_pack_wd(const float* Wd, fp8* dst) {
    const size_t n = (size_t)WDR * KDd;
    for (size_t i = (size_t)blockIdx.x * blockDim.x + threadIdx.x; i < n;
         i += (size_t)gridDim.x * blockDim.x) {
        int r = (int)(i / KDd), k = (int)(i % KDd);
        float v = (r < Fdim) ? Wd[(size_t)r * KDd + k] : 0.f;
        dst[i] = f2fp8(v * SW);
    }
}

__global__ void k_pack_bias(const float* bi1, const float* bh1,
                            const float* bi2, const float* bh2,
                            const float* bi3, const float* bh3,
                            const float* bd,
                            float* B1, float* B2, float* B3, float* BD) {
    const int n = 3 * NG + WDR;
    for (int i = blockIdx.x * blockDim.x + threadIdx.x; i < n;
         i += gridDim.x * blockDim.x) {
        if (i < NG)            { int ro = orig_row(i);        B1[i]        = bi1[ro] + bh1[ro]; }
        else if (i < 2 * NG)   { int ro = orig_row(i - NG);   B2[i - NG]   = bi2[ro] + bh2[ro]; }
        else if (i < 3 * NG)   { int ro = orig_row(i - 2*NG); B3[i - 2*NG] = bi3[ro] + bh3[ro]; }
        else { int r = i - 3 * NG; BD[r] = (r < Fdim) ? bd[r] : 0.f; }
    }
}

// zero all rotating state slots with coherent stores (no cached copies anywhere)
__global__ void k_init(fp8* ab1, fp8* ab2, fp8* ab3, float* cb, unsigned* bar, int D) {
    const size_t n1 = (size_t)D * (S1e / 8);   // u64 count
    const size_t n2 = (size_t)D * (S2e / 8);
    const size_t nc = 3 * Bn * Hdim;
    const size_t tot = n1 + 2 * n2 + nc + 512;
    for (size_t i = (size_t)blockIdx.x * blockDim.x + threadIdx.x; i < tot;
         i += (size_t)gridDim.x * blockDim.x) {
        if (i < n1)             stu64((unsigned long long*)ab1 + i, 0ull);
        else if (i < n1 + n2)   stu64((unsigned long long*)ab2 + (i - n1), 0ull);
        else if (i < n1 + 2*n2) stu64((unsigned long long*)ab3 + (i - n1 - n2), 0ull);
        else if (i < n1 + 2*n2 + nc) cb[i - n1 - 2*n2] = 0.f;
        else bar[i - n1 - 2*n2 - nc] = 0u;
    }
}

// stage x(0) into slot 0 (tiled layout), coherent, scaled by SA
__global__ void k_stage0(const float* xseq, fp8* ab1, int T0) {
    for (int idx = blockIdx.x * blockDim.x + threadIdx.x; idx < Bn * 11 * 16;
         idx += gridDim.x * blockDim.x) {
        int fu = idx >> 9, rem = idx & 511, b = rem >> 4, jj = rem & 15;
        int f = fu * 16 + jj;
        if (f < Fdim)
            st1c(&ab1[idx], f2fp8(xseq[(size_t)b * T0 * Fdim + f] * SA));
    }
}

__global__ void k_copy_orig(const float* xseq, float* out, int T, int T0) {
    const int n = Bn * T0 * Fdim;
    const size_t base = (size_t)Bn * T * Fdim;
    for (int i = blockIdx.x * blockDim.x + threadIdx.x; i < n;
         i += gridDim.x * blockDim.x) {
        out[base + i] = xseq[i];
    }
}

// ---------------- fence-free grid barriers (flag array, relaxed atomics) ----
__device__ __forceinline__ void gbar_all(unsigned* flags, unsigned target) {
    __syncthreads();   // drains vmcnt: all state stores acked before flag
    const int tid = threadIdx.x;
    if (tid == 0)
        __hip_atomic_store(&flags[blockIdx.x], target, __ATOMIC_RELAXED,
                           __HIP_MEMORY_SCOPE_AGENT);
    if (tid < 64) {
        for (;;) {
            unsigned v0 = __hip_atomic_load(&flags[tid], __ATOMIC_RELAXED,
                                            __HIP_MEMORY_SCOPE_AGENT);
            unsigned v1 = __hip_atomic_load(&flags[tid + 64], __ATOMIC_RELAXED,
                                            __HIP_MEMORY_SCOPE_AGENT);
            unsigned v2 = __hip_atomic_load(&flags[tid + 128], __ATOMIC_RELAXED,
                                            __HIP_MEMORY_SCOPE_AGENT);
            if (__all(v0 >= target && v1 >= target && v2 >= target)) break;
            __builtin_amdgcn_s_sleep(1);
        }
    }
    asm volatile("" ::: "memory");
    __syncthreads();
}

__device__ __forceinline__ void gbar64(unsigned* flags, unsigned target) {
    __syncthreads();
    const int tid = threadIdx.x;
    if (tid == 0)
        __hip_atomic_store(&flags[blockIdx.x], target, __ATOMIC_RELAXED,
                           __HIP_MEMORY_SCOPE_AGENT);
    if (tid < 64) {
        for (;;) {
            unsigned v = __hip_atomic_load(&flags[tid], __ATOMIC_RELAXED,
                                           __HIP_MEMORY_SCOPE_AGENT);
            if (__all(v >= target)) break;
            __builtin_amdgcn_s_sleep(1);
        }
    }
    asm volatile("" ::: "memory");
    __syncthreads();
}

// ---------------- phase-A gate GEMM (fp8) ----------------
// State A is tiled [k/16][b][16] fp8; weights row-linear [gate_row][k] fp8.
// 8 waves split K 8 ways; plain cached loads everywhere.
template <int K, int NF>
__device__ __forceinline__ void gemmA(const fp8* __restrict__ As,
                                      const fp8* __restrict__ Wrow,
                                      float (&red)[8][32][66],
                                      int w, int lane) {
    const int col = lane & 15;
    const int kb8 = (lane >> 4) << 3;
    const int k0 = w * (K / 8);

    long a0[NF], a1[NF];
#pragma unroll
    for (int i = 0; i < NF; ++i) {
        int k = k0 + i * 32 + kb8;
        const fp8* ap = As + (size_t)(k >> 4) * 512 + (k & 15);
        a0[i] = ld8b(ap + col * 16);
        a1[i] = ld8b(ap + (col + 16) * 16);
    }
    f32x4 acc[2][4] = {};
#pragma unroll
    for (int i = 0; i < NF; ++i) {
        const fp8* wp = Wrow + (size_t)col * K + k0 + i * 32 + kb8;
#pragma unroll
        for (int q = 0; q < 4; ++q) {
            long bq = ld8b(wp + (size_t)q * 16 * K);
            acc[0][q] = mfma8(a0[i], bq, acc[0][q]);
            acc[1][q] = mfma8(a1[i], bq, acc[1][q]);
        }
    }
    __syncthreads();  // protect red[] from previous phase's readers
#pragma unroll
    for (int mt = 0; mt < 2; ++mt)
#pragma unroll
        for (int q = 0; q < 4; ++q)
#pragma unroll
            for (int r = 0; r < 4; ++r)
                red[w][mt * 16 + (lane >> 4) * 4 + r][q * 16 + col] = acc[mt][q][r];
    __syncthreads();
}

// ---------------- persistent LSTM kernel ----------------
// grid = 192 x 512 threads (8 waves). block -> (layer = bid/64, ut = bid%64).
// Rotating state slots (D deep): step t reads slot t&dm, writes slot (t+1)&dm.
__global__ __launch_bounds__(512, 1) void k_lstm(
    const float* __restrict__ xseq, float* __restrict__ out,
    const fp8* __restrict__ W1, const fp8* __restrict__ W2,
    const fp8* __restrict__ W3, const fp8* __restrict__ WD,
    const float* __restrict__ b1, const float* __restrict__ b2,
    const float* __restrict__ b3, const float* __restrict__ bdp,
    fp8* ab1, fp8* ab2, fp8* ab3, float* cb,
    unsigned* bar, int T0, int T, int dm) {
    __shared__ float red[8][32][66];

    const int tid = threadIdx.x;
    const int w = tid >> 6;
    const int lane = tid & 63;
    const int col = lane & 15;
    const int kb8 = (lane >> 4) << 3;
    const int bid = blockIdx.x;
    const int layer = bid >> 6;
    const int ut = bid & 63;

    unsigned* flagsA = bar;
    unsigned* flagsB = bar + 256;

    const fp8* Wl = (layer == 0) ? W1 : (layer == 1) ? W2 : W3;
    const float* bl = (layer == 0) ? b1 : (layer == 1) ? b2 : b3;
    fp8* abIn = (layer == 0) ? ab1 : (layer == 1) ? ab2 : ab3;
    const size_t Sl = (layer == 0) ? (size_t)S1e : (size_t)S2e;
    const int Kl = (layer == 0) ? K1p : K2c;

    const int eb = tid >> 4;      // elementwise batch row
    const int ejj = tid & 15;     // elementwise unit-within-tile

    for (int t = 0; t < T; ++t) {
        const int st = t & dm;
        const int ns = (t + 1) & dm;

        // ---------- phase A: gate GEMM + state update ----------
        {
            const fp8* As = abIn + (size_t)st * Sl;
            const fp8* Wrow = Wl + (size_t)(ut * 64) * Kl;
            if (layer == 0) gemmA<K1p, 5>(As, Wrow, red, w, lane);
            else            gemmA<K2c, 8>(As, Wrow, red, w, lane);

            float s[4];
#pragma unroll
            for (int q = 0; q < 4; ++q) {
                float a = 0.f;
#pragma unroll
                for (int ww = 0; ww < 8; ++ww) a += red[ww][eb][q * 16 + ejj];
                s[q] = a * INVS + bl[ut * 64 + q * 16 + ejj];
            }
            size_t cidx = ((size_t)layer * Bn + eb) * Hdim + ut * 16 + ejj;
            float cold = cb[cidx];
            float cn = sigm(s[1]) * cold + sigm(s[0]) * tanhf(s[2]);
            float hn = sigm(s[3]) * tanhf(cn);
            cb[cidx] = cn;
            unsigned char hq = f2fp8(hn * SA);
            const int off = eb * 16 + ejj;
            if (layer == 0) {
                st1c(ab1 + (size_t)ns * S1e + (11 + ut) * 512 + off, hq);
                st1c(ab2 + (size_t)ns * S2e + ut * 512 + off, hq);
            } else if (layer == 1) {
                st1c(ab2 + (size_t)ns * S2e + (64 + ut) * 512 + off, hq);
                st1c(ab3 + (size_t)ns * S2e + ut * 512 + off, hq);
            } else {
                st1c(ab3 + (size_t)ns * S2e + (64 + ut) * 512 + off, hq);
            }

            if (bid == 11 && t + 1 < T0) {  // stage conditioned x(t+1), tiled
                fp8* dst = ab1 + (size_t)ns * S1e;
                for (int idx = tid; idx < Bn * 11 * 16; idx += 512) {
                    int fu = idx >> 9, rem = idx & 511, b = rem >> 4, jj = rem & 15;
                    int f = fu * 16 + jj;
                    if (f < Fdim)
                        st1c(dst + idx,
                             f2fp8(xseq[((size_t)b * T0 + t + 1) * Fdim + f] * SA));
                }
            }
        }
        gbar_all(flagsA, (unsigned)(t + 1));

        // ---------- phase B: decoder (+feedback) ----------
        if (bid < 11) {
            const fp8* As = ab3 + (size_t)ns * S2e + 64 * 512;  // h2 tiles
            const fp8* Wrowd = WD + (size_t)(bid * 16) * KDd;
            const int dk0 = w * 128;
            long da0[4], da1[4];
#pragma unroll
            for (int i = 0; i < 4; ++i) {
                int k = dk0 + i * 32 + kb8;
                const fp8* ap = As + (size_t)(k >> 4) * 512 + (k & 15);
                da0[i] = ld8b(ap + col * 16);
                da1[i] = ld8b(ap + (col + 16) * 16);
            }
            f32x4 dacc[2] = {};
#pragma unroll
            for (int i = 0; i < 4; ++i) {
                long bq = ld8b(Wrowd + (size_t)col * KDd + dk0 + i * 32 + kb8);
                dacc[0] = mfma8(da0[i], bq, dacc[0]);
                dacc[1] = mfma8(da1[i], bq, dacc[1]);
            }
            __syncthreads();
#pragma unroll
            for (int mt = 0; mt < 2; ++mt)
#pragma unroll
                for (int r = 0; r < 4; ++r)
                    red[w][mt * 16 + (lane >> 4) * 4 + r][col] = dacc[mt][r];
            __syncthreads();
            {
                int f = bid * 16 + ejj;
                float v = 0.f;
#pragma unroll
                for (int ww = 0; ww < 8; ++ww) v += red[ww][eb][ejj];
                v = v * INVS + bdp[f];
                if (f < Fdim) {
                    out[(size_t)eb * ((size_t)T * Fdim) + (size_t)t * Fdim + f] = v;
                    if (t >= T0 - 1)  // out(t) = x(t+1) in the generative phase
                        st1c(ab1 + (size_t)ns * S1e + bid * 512 + eb * 16 + ejj,
                             f2fp8(v * SA));
                }
            }
        }
        if (t >= T0 - 1 && bid < 64)
            gbar64(flagsB, (unsigned)(t - T0 + 2));
    }
}

// ---------------- host launch ----------------
extern "C" void kernel_launch(void* const* d_in, const int* in_sizes, int n_in,
                              void* d_out, int out_size, void* d_ws, size_t ws_size,
                              hipStream_t stream) {
    const float* xseq = (const float*)d_in[0];
    const float* Wih1 = (const float*)d_in[2];
    const float* Whh1 = (const float*)d_in[3];
    const float* bih1 = (const float*)d_in[4];
    const float* bhh1 = (const float*)d_in[5];
    const float* Wih2 = (const float*)d_in[6];
    const float* Whh2 = (const float*)d_in[7];
    const float* bih2 = (const float*)d_in[8];
    const float* bhh2 = (const float*)d_in[9];
    const float* Wih3 = (const float*)d_in[10];
    const float* Whh3 = (const float*)d_in[11];
    const float* bih3 = (const float*)d_in[12];
    const float* bhh3 = (const float*)d_in[13];
    const float* Wd   = (const float*)d_in[14];
    const float* bd   = (const float*)d_in[15];

    const int T0 = in_sizes[0] / (Bn * Fdim);                 // 50
    const int T  = out_size / (Bn * Fdim) - T0;               // 350

    char* ws = (char*)d_ws;
    fp8*   pW1 = (fp8*)(ws + OFF_W1);
    fp8*   pW2 = (fp8*)(ws + OFF_W2);
    fp8*   pW3 = (fp8*)(ws + OFF_W3);
    fp8*   pWD = (fp8*)(ws + OFF_WD);
    float* pB1 = (float*)(ws + OFF_B1);
    float* pB2 = (float*)(ws + OFF_B2);
    float* pB3 = (float*)(ws + OFF_B3);
    float* pBD = (float*)(ws + OFF_BD);
    float* cbp = (float*)(ws + OFF_CB);
    unsigned* bar = (unsigned*)(ws + OFF_BAR);
    float* out = (float*)d_out;

    // rotation depth: largest power-of-2 D (<=32) whose state fits in ws
    int D = 32;
    while (D > 4 &&
           OFF_AB1 + (size_t)D * ((size_t)S1e + 2 * (size_t)S2e) > ws_size)
        D >>= 1;
    fp8* ab1 = (fp8*)(ws + OFF_AB1);
    fp8* ab2 = ab1 + (size_t)D * S1e;
    fp8* ab3 = ab2 + (size_t)D * S2e;

    (void)n_in;  // total need @D=32 ~= 28 MB

    hipLaunchKernelGGL(k_pack_w1, dim3(1024), dim3(256), 0, stream, Wih1, Whh1, pW1);
    hipLaunchKernelGGL(k_pack_w23, dim3(1024), dim3(256), 0, stream, Wih2, Whh2, pW2);
    hipLaunchKernelGGL(k_pack_w23, dim3(1024), dim3(256), 0, stream, Wih3, Whh3, pW3);
    hipLaunchKernelGGL(k_pack_wd, dim3(704), dim3(256), 0, stream, Wd, pWD);
    hipLaunchKernelGGL(k_pack_bias, dim3(49), dim3(256), 0, stream,
                       bih1, bhh1, bih2, bhh2, bih3, bhh3, bd, pB1, pB2, pB3, pBD);
    hipLaunchKernelGGL(k_init, dim3(2048), dim3(256), 0, stream,
                       ab1, ab2, ab3, cbp, bar, D);
    hipLaunchKernelGGL(k_stage0, dim3(22), dim3(256), 0, stream, xseq, ab1, T0);
    hipLaunchKernelGGL(k_lstm, dim3(NBLK), dim3(512), 0, stream,
                       xseq, out, pW1, pW2, pW3, pWD, pB1, pB2, pB3, pBD,
                       ab1, ab2, ab3, cbp, bar, T0, T, D - 1);
    hipLaunchKernelGGL(k_copy_orig, dim3(1069), dim3(256), 0, stream, xseq, out, T, T0);
}